// Round 13
// baseline (274.381 us; speedup 1.0000x reference)
//
#include <hip/hip_runtime.h>
#include <math.h>

// Problem constants
#define BB 2

// ws layout (float offsets)
#define WS_PPART 0         // 2*128*256 pool partials
#define WS_GLOB  66048     // 2*256
#define WS_KVP   66560     // 16*32*1024 KV partials
#define WS_KSP   590848    // 16*32*32 Ksum partials
#define WS_KVT   607232    // bf16 KV_aug: 16*48*32 ushort
#define WS_WFP   619520    // bf16 Wf pre-tiled [16][256][32]: 131072 ushort
#define WS_L1T   685056    // bf16 l1 pre-tiled: 2*8*128*32 ushort
#define WS_L2T   717824
#define WS_KWT   750592
#define WS_VWT   783360

typedef __attribute__((ext_vector_type(8))) short short8v;
typedef __attribute__((ext_vector_type(4))) float f32x4;

__device__ __forceinline__ ushort f2bf(float x) {
    union { float f; unsigned int u; } v; v.f = x;
    unsigned int u = v.u;
    unsigned int r = (u + 0x7fffu + ((u >> 16) & 1u)) >> 16;
    return (ushort)r;
}

__device__ __forceinline__ float bf2f(ushort x) {
    union { float f; unsigned int u; } v;
    v.u = ((unsigned int)x) << 16;
    return v.f;
}

// packed f32x2 -> bf16x2 (RNE), 1 VALU op
__device__ __forceinline__ unsigned int cvtpk(float lo, float hi) {
    unsigned int d;
    asm("v_cvt_pk_bf16_f32 %0, %1, %2" : "=v"(d) : "v"(lo), "v"(hi));
    return d;
}

// async global->LDS, 16B per lane; LDS dest is wave-uniform base (+lane*16 by HW)
__device__ __forceinline__ void gload16(const void* g, void* l) {
    __builtin_amdgcn_global_load_lds(
        (const __attribute__((address_space(1))) unsigned int*)g,
        (__attribute__((address_space(3))) unsigned int*)l, 16, 0, 0);
}

// ---------------- merged prep: weight tiling + Wf fuse + pool partials (R7-exact) ----------------
__global__ __launch_bounds__(256) void k_prep(const float* __restrict__ l1w, const float* __restrict__ l2w,
                                              const float* __restrict__ kw, const float* __restrict__ vw,
                                              const float* __restrict__ mh, const float* __restrict__ qw,
                                              const float* __restrict__ key,
                                              ushort* __restrict__ t0, ushort* __restrict__ t1,
                                              ushort* __restrict__ t2, ushort* __restrict__ t3,
                                              ushort* __restrict__ wfp, float* __restrict__ ppart) {
    int blk = blockIdx.x, t = threadIdx.x;
    if (blk < 1024) {
        int mat = blk >> 8, k = blk & 255, n = t;
        const float* w = mat == 0 ? l1w : mat == 1 ? l2w : mat == 2 ? kw : vw;
        ushort* o = mat == 0 ? t0 : mat == 1 ? t1 : mat == 2 ? t2 : t3;
        o[(((size_t)(n >> 7) * 8 + (k >> 5)) * 128 + (n & 127)) * 32 + (k & 31)] = f2bf(w[k * 256 + n]);
    } else if (blk < 1536) {
        __shared__ float mr[256];
        int g = blk - 1024;
        mr[t] = mh[g * 256 + t];
        __syncthreads();
        float acc = 0.f;
        for (int k = 0; k < 256; k++) acc += mr[k] * qw[k * 256 + t];
        wfp[(((size_t)(g >> 5) * 256 + t) * 32 + (g & 31))] = f2bf(acc);
    } else {
        int p = blk - 1536;
        int b = p >> 7, ci = p & 127;
        float acc = 0.f;
        for (int q = 0; q < 128; q++) {
            size_t idx = ((size_t)b * 65536 + (size_t)(2 * ci + 1) * 256 + (2 * q + 1)) * 256 + t;
            acc += key[idx];
        }
        ppart[(size_t)p * 256 + t] = acc;
    }
}

// ---------------- pool reduce + glob (single block, R7-exact) ----------------
__global__ __launch_bounds__(256) void k_glob2(const float* __restrict__ ppart,
                                               const float* __restrict__ g1w,
                                               const float* __restrict__ g1b,
                                               const float* __restrict__ g2w,
                                               const float* __restrict__ g2b,
                                               float* __restrict__ glob) {
    __shared__ float pl[256], hid[256];
    int t = threadIdx.x;
    for (int b = 0; b < BB; b++) {
        float s = 0.f;
        for (int p = 0; p < 128; p++) s += ppart[((size_t)b * 128 + p) * 256 + t];
        pl[t] = s * (2.f / 16384.f);
        __syncthreads();
        float acc = g1b[t];
        for (int k = 0; k < 256; k++) acc += pl[k] * g1w[k * 256 + t];
        hid[t] = fmaxf(acc, 0.f);
        __syncthreads();
        float a2 = g2b[t];
        for (int k = 0; k < 256; k++) a2 += hid[k] * g2w[k * 256 + t];
        glob[b * 256 + t] = a2;
        __syncthreads();
    }
}

// ---------------- bf16 MFMA mid GEMM: 128x128 tile, K=256, M=32768 (R4/R7-proven) ----------------
template <int AMODE, int EPI>
__global__ __launch_bounds__(256) void gemm_bf(const void* __restrict__ Asrc_,
                                               const ushort* __restrict__ Wt,
                                               const float* __restrict__ bias,
                                               void* __restrict__ Outp,
                                               const float* __restrict__ glob,
                                               const float* __restrict__ key) {
    __shared__ __align__(16) ushort smem[8192];   // As 8KB | Bs 8KB
    ushort* As = smem;
    ushort* Bs = smem + 4096;

    const int tid = threadIdx.x;
    const int lane = tid & 63;
    const int w = tid >> 6;
    const int wrow = w >> 1, wcol = w & 1;
    const int bx = blockIdx.x & 1;
    const int by = blockIdx.x >> 1;
    const int r0 = by * 128, n0 = bx * 128;
    const int l15 = lane & 15, l4 = lane >> 4;

    const int loff = lane * 16;
    char* ldsB0 = (char*)Bs + w * 2048;
    char* ldsB1 = (char*)Bs + w * 2048 + 1024;
    const int rowA0 = w * 32 + (lane >> 2);
    const int kbA = (lane & 3) * 16;
    char* ldsA0 = (char*)As + w * 2048;
    char* ldsA1 = (char*)As + w * 2048 + 1024;
    const int srow = tid >> 1, shalf = tid & 1;
    size_t agbase = 0;
    if constexpr (AMODE == 1) {
        int r = r0 + srow;
        int b = r >> 14, rr = r & 16383;
        int ii = rr >> 7, jj = rr & 127;
        agbase = ((size_t)b * 65536 + (size_t)(2 * ii + 1) * 256 + (2 * jj + 1)) * 256 + shalf * 16;
    }

    f32x4 acc[4][4];
#pragma unroll
    for (int i = 0; i < 4; i++)
#pragma unroll
        for (int j = 0; j < 4; j++) acc[i][j] = (f32x4){0.f, 0.f, 0.f, 0.f};

    for (int ks = 0; ks < 8; ks++) {
        const char* btile = (const char*)Wt + (size_t)(bx * 8 + ks) * 8192;
        gload16(btile + w * 2048 + loff, ldsB0);
        gload16(btile + w * 2048 + 1024 + loff, ldsB1);
        if constexpr (AMODE == 0) {
            const char* ab = (const char*)Asrc_;
            gload16(ab + (size_t)(r0 + rowA0) * 512 + ks * 64 + kbA, ldsA0);
            gload16(ab + (size_t)(r0 + rowA0 + 16) * 512 + ks * 64 + kbA, ldsA1);
        } else {
            const float* kf = (const float*)Asrc_;
            float4 f0 = *(const float4*)(kf + agbase + (size_t)ks * 32);
            float4 f1 = *(const float4*)(kf + agbase + (size_t)ks * 32 + 4);
            float4 f2 = *(const float4*)(kf + agbase + (size_t)ks * 32 + 8);
            float4 f3 = *(const float4*)(kf + agbase + (size_t)ks * 32 + 12);
            uint4 lo = {cvtpk(f0.x * 2.f, f0.y * 2.f), cvtpk(f0.z * 2.f, f0.w * 2.f),
                        cvtpk(f1.x * 2.f, f1.y * 2.f), cvtpk(f1.z * 2.f, f1.w * 2.f)};
            uint4 hi = {cvtpk(f2.x * 2.f, f2.y * 2.f), cvtpk(f2.z * 2.f, f2.w * 2.f),
                        cvtpk(f3.x * 2.f, f3.y * 2.f), cvtpk(f3.z * 2.f, f3.w * 2.f)};
            *(uint4*)((char*)As + srow * 64 + shalf * 32) = lo;
            *(uint4*)((char*)As + srow * 64 + shalf * 32 + 16) = hi;
        }
        __syncthreads();

        short8v a[4], bfr[4];
#pragma unroll
        for (int m = 0; m < 4; m++)
            a[m] = *(const short8v*)((const char*)As + (wrow * 64 + m * 16 + l15) * 64 + l4 * 16);
#pragma unroll
        for (int n = 0; n < 4; n++)
            bfr[n] = *(const short8v*)((const char*)Bs + (wcol * 64 + n * 16 + l15) * 64 + l4 * 16);
#pragma unroll
        for (int m = 0; m < 4; m++)
#pragma unroll
            for (int n = 0; n < 4; n++)
                acc[m][n] = __builtin_amdgcn_mfma_f32_16x16x32_bf16(a[m], bfr[n], acc[m][n], 0, 0, 0);
        __syncthreads();
    }

    const int b = r0 >> 14;
    float bv[4], gv[4];
#pragma unroll
    for (int n = 0; n < 4; n++) {
        int c = n0 + wcol * 64 + n * 16 + l15;
        bv[n] = bias[c];
        if constexpr (EPI == 1) gv[n] = glob[b * 256 + c];
    }
#pragma unroll
    for (int m = 0; m < 4; m++) {
#pragma unroll
        for (int n = 0; n < 4; n++) {
            int c = n0 + wcol * 64 + n * 16 + l15;
#pragma unroll
            for (int r = 0; r < 4; r++) {
                int row = wrow * 64 + m * 16 + l4 * 4 + r;
                int R = r0 + row;
                float x = acc[m][n][r] + bv[n];
                if constexpr (EPI == 0) {
                    ((ushort*)Outp)[(size_t)R * 256 + c] = f2bf(fmaxf(x, 0.f));
                } else if constexpr (EPI == 1) {
                    int rr = R & 16383;
                    int ii = rr >> 7, jj = rr & 127;
                    size_t kb = ((size_t)b * 65536 + (size_t)(2 * ii) * 256 + 2 * jj) * 256 + c;
                    float ka = key[kb];
                    float kb2 = key[kb + 256];
                    float kc2 = key[kb + 65536];
                    float kd2 = key[kb + 65536 + 256];
                    float low = 0.5f * (ka + kb2 + kc2 + kd2);
                    float high = 0.5f * (3.f * kd2 - ka - kb2 - kc2);
                    float wei = 1.f / (1.f + __expf(-(x + gv[n])));
                    ((ushort*)Outp)[(size_t)R * 256 + c] = f2bf(wei * high + low);
                } else if constexpr (EPI == 4) {
                    ((ushort*)Outp)[(size_t)R * 256 + c] = f2bf((x > 0.f) ? x + 1.f : __expf(x));
                } else {
                    ((ushort*)Outp)[(size_t)R * 256 + c] = f2bf(x);
                }
            }
        }
    }
}

// ---------------- KV partials (bf16 in, R7-exact 8-row stages) ----------------
__global__ __launch_bounds__(256) void k_kv_part(const ushort* __restrict__ Km,
                                                 const ushort* __restrict__ Vn,
                                                 float* __restrict__ kvp,
                                                 float* __restrict__ ksp) {
    __shared__ float Kl[8][33];
    __shared__ float Vl[8][33];
    int t = threadIdx.x;
    int c = blockIdx.x & 31, h = (blockIdx.x >> 5) & 7, b = blockIdx.x >> 8;
    int d = t >> 3, vq = (t & 7) * 4;
    int lr = t >> 5, lc = t & 31;
    float acc0 = 0, acc1 = 0, acc2 = 0, acc3 = 0, ks = 0;
    size_t rowbase = (size_t)b * 16384 + (size_t)c * 512;
    for (int s0 = 0; s0 < 512; s0 += 8) {
        size_t idx = (rowbase + s0 + lr) * 256 + h * 32 + lc;
        Kl[lr][lc] = bf2f(Km[idx]);
        Vl[lr][lc] = bf2f(Vn[idx]);
        __syncthreads();
#pragma unroll
        for (int rr = 0; rr < 8; rr++) {
            float kd = Kl[rr][d];
            acc0 += kd * Vl[rr][vq];
            acc1 += kd * Vl[rr][vq + 1];
            acc2 += kd * Vl[rr][vq + 2];
            acc3 += kd * Vl[rr][vq + 3];
            ks += kd;
        }
        __syncthreads();
    }
    size_t ob = ((size_t)(b * 8 + h) * 32 + c) * 1024 + d * 32 + vq;
    kvp[ob] = acc0; kvp[ob + 1] = acc1; kvp[ob + 2] = acc2; kvp[ob + 3] = acc3;
    if ((t & 7) == 0) ksp[((b * 8 + h) * 32 + c) * 32 + d] = ks;
}

// ---------------- KV reduce -> bf16 augmented B^T: KVt[bh][48][32] (R7-exact) ----------------
__global__ __launch_bounds__(256) void k_kv_reduce(const float* __restrict__ kvp,
                                                   const float* __restrict__ ksp,
                                                   ushort* __restrict__ kvt) {
    int bh = blockIdx.x, t = threadIdx.x;
    for (int e = t; e < 1024; e += 256) {
        float s = 0.f;
        for (int cc = 0; cc < 32; cc++) s += kvp[((size_t)bh * 32 + cc) * 1024 + e];
        int d = e >> 5, v = e & 31;
        kvt[((size_t)bh * 48 + v) * 32 + d] = f2bf(s);
    }
    if (t < 32) {
        float s = 0.f;
        for (int cc = 0; cc < 32; cc++) s += ksp[(bh * 32 + cc) * 32 + t];
        kvt[((size_t)bh * 48 + 32) * 32 + t] = f2bf(s);
    }
    for (int z = t; z < 480; z += 256) kvt[(size_t)bh * 48 * 32 + 33 * 32 + z] = 0;
}

// ---------------- MFMA q-GEMM: A tri-buffer counted-vmcnt DMA, B global->VGPR (L2) ----------------
// 512 threads, 8 waves (2 wrow x 4 wcol). A: 3 x 16KB f32 stages, vmcnt(2) never drains to 0.
// B fragments read directly from the L2-resident 256KB pre-tiled wfp panel (16B/lane coalesced,
// compiler-managed waits; issued BEFORE the A-stage DMAs so B-waits leave A's loads in flight).
// LDS declared 64KB for the epilogue Q-tile overlay (occupancy unchanged: 2 blocks/CU).
__global__ __launch_bounds__(512, 4) void k_qattn_mfma(const float* __restrict__ query,
                                                       const ushort* __restrict__ wfp,
                                                       const float* __restrict__ qb,
                                                       const ushort* __restrict__ kvt,
                                                       float* __restrict__ Out) {
    __shared__ __align__(16) char smem[65536];   // A stages: 3 x 16KB; epilogue overlays 64KB

    const int tid = threadIdx.x;
    const int lane = tid & 63;
    const int wid = tid >> 6;            // 0..7
    const int wrow = wid >> 2, wcol = wid & 3;
    const int R0 = blockIdx.x * 128;
    const int l15 = lane & 15, l4 = lane >> 4;

    // A staging: rows wid*16 + j*8 + (lane>>3), chunk (lane&7)^(lane>>3) (pre-swizzled source)
    const int arow0 = wid * 16 + (lane >> 3);
    const int achunk = (lane & 7) ^ (lane >> 3);
    const float* aga = query + (size_t)(R0 + arow0) * 512 + achunk * 4;
    const int wb = wid * 2048;

    f32x4 acc[4][4];
#pragma unroll
    for (int i = 0; i < 4; i++)
#pragma unroll
        for (int j = 0; j < 4; j++) acc[i][j] = (f32x4){0.f, 0.f, 0.f, 0.f};

#define QSTAGE(buf, kss)                                                        \
    do {                                                                        \
        char* dA_ = smem + (buf) * 16384;                                       \
        const float* ga_ = aga + (size_t)(kss) * 32;                            \
        gload16(ga_, dA_ + wb);                                                 \
        gload16(ga_ + 8 * 512, dA_ + wb + 1024);                                \
    } while (0)

    // prologue: stages 0 and 1 in flight (4 loads/thread)
    QSTAGE(0, 0);
    QSTAGE(1, 1);

    int cur = 0, nxt2 = 2;
    for (int ks = 0; ks < 16; ks++) {
        // A(ks) landed when <=2 outstanding (the 2 youngest are A(ks+1)'s)
        asm volatile("s_waitcnt vmcnt(2)" ::: "memory");
        __builtin_amdgcn_s_barrier();
        __builtin_amdgcn_sched_barrier(0);

        // B fragments: global->VGPR from L2-resident panel (issued before next A stage)
        const char* pan = (const char*)wfp + (size_t)ks * 16384;
        short8v bfr[4];
#pragma unroll
        for (int n = 0; n < 4; n++)
            bfr[n] = *(const short8v*)(pan + (wcol * 64 + n * 16 + l15) * 64 + l4 * 16);

        if (ks + 2 < 16) QSTAGE(nxt2, ks + 2);

        const char* bA = smem + cur * 16384;
#pragma unroll
        for (int m = 0; m < 4; m++) {
            int row = wrow * 64 + m * 16 + l15;
            int j0 = (l4 * 2) ^ (l15 & 7);
            const char* rp = bA + row * 128;
            f32x4 lo = *(const f32x4*)(rp + j0 * 16);
            f32x4 hi = *(const f32x4*)(rp + (j0 ^ 1) * 16);
            union { uint4 u; short8v s; } av;
            av.u = (uint4){cvtpk(lo.x, lo.y), cvtpk(lo.z, lo.w),
                           cvtpk(hi.x, hi.y), cvtpk(hi.z, hi.w)};
#pragma unroll
            for (int n = 0; n < 4; n++)
                acc[m][n] = __builtin_amdgcn_mfma_f32_16x16x32_bf16(av.s, bfr[n], acc[m][n], 0, 0, 0);
        }

        cur = cur == 2 ? 0 : cur + 1;
        nxt2 = nxt2 == 2 ? 0 : nxt2 + 1;
    }
#undef QSTAGE

    __syncthreads();   // drains everything; all frag reads done before Q-tile overlays smem

    // Q = elu(x+qb)+1 -> per-wave region [64][64] bf16, XOR-swizzled
    float qbv[4];
#pragma unroll
    for (int n = 0; n < 4; n++) qbv[n] = qb[wcol * 64 + n * 16 + l15];
#pragma unroll
    for (int m = 0; m < 4; m++) {
#pragma unroll
        for (int n = 0; n < 4; n++) {
#pragma unroll
            for (int r = 0; r < 4; r++) {
                int rl = m * 16 + l4 * 4 + r;
                int cl = n * 16 + l15;
                float x = acc[m][n][r] + qbv[n];
                float q = x > 0.f ? x + 1.f : __expf(x);
                int byte = wid * 8192 + ((rl * 128 + cl * 2) ^ ((rl & 7) << 4));
                *(ushort*)(smem + byte) = f2bf(q);
            }
        }
    }
    __syncthreads();

    // attention epilogue: wave's 2 heads; O = Q_h @ KV_aug (cols 0..31 KV, col 32 Ksum)
    const int bb = R0 >> 16;
#pragma unroll
    for (int hi = 0; hi < 2; hi++) {
        int h = wcol * 2 + hi;
        int bh = bb * 8 + h;
        const ushort* kb = kvt + (size_t)bh * 48 * 32;
        short8v bk0 = *(const short8v*)(kb + (0 * 16 + l15) * 32 + l4 * 8);
        short8v bk1 = *(const short8v*)(kb + (1 * 16 + l15) * 32 + l4 * 8);
        short8v bkz = *(const short8v*)(kb + (2 * 16 + l15) * 32 + l4 * 8);
#pragma unroll
        for (int m = 0; m < 4; m++) {
            int rl = m * 16 + l15;
            int byte = wid * 8192 + ((rl * 128 + hi * 64 + l4 * 16) ^ ((rl & 7) << 4));
            short8v aq = *(const short8v*)(smem + byte);
            f32x4 zero = (f32x4){0.f, 0.f, 0.f, 0.f};
            f32x4 o0 = __builtin_amdgcn_mfma_f32_16x16x32_bf16(aq, bk0, zero, 0, 0, 0);
            f32x4 o1 = __builtin_amdgcn_mfma_f32_16x16x32_bf16(aq, bk1, zero, 0, 0, 0);
            f32x4 oz = __builtin_amdgcn_mfma_f32_16x16x32_bf16(aq, bkz, zero, 0, 0, 0);
#pragma unroll
            for (int r = 0; r < 4; r++) {
                float z = __shfl(oz[r], (lane & 48));
                float sc = 1.f / (z + 1e-6f);
                int grow = R0 + wrow * 64 + m * 16 + l4 * 4 + r;
                int gcol = wcol * 64 + hi * 32 + l15;
                Out[(size_t)grow * 256 + gcol] = o0[r] * sc;
                Out[(size_t)grow * 256 + gcol + 16] = o1[r] * sc;
            }
        }
    }
}

extern "C" void kernel_launch(void* const* d_in, const int* in_sizes, int n_in,
                              void* d_out, int out_size, void* d_ws, size_t ws_size,
                              hipStream_t stream) {
    const float* query = (const float*)d_in[0];
    const float* key = (const float*)d_in[1];
    // d_in[2] = value: only its shape is used by the reference — never read.
    const float* mh = (const float*)d_in[3];
    const float* q_w = (const float*)d_in[4];
    const float* q_b = (const float*)d_in[5];
    const float* k_w = (const float*)d_in[6];
    const float* k_b = (const float*)d_in[7];
    const float* v_w = (const float*)d_in[8];
    const float* v_b = (const float*)d_in[9];
    const float* l1_w = (const float*)d_in[10];
    const float* l1_b = (const float*)d_in[11];
    const float* l2_w = (const float*)d_in[12];
    const float* l2_b = (const float*)d_in[13];
    const float* g1_w = (const float*)d_in[14];
    const float* g1_b = (const float*)d_in[15];
    const float* g2_w = (const float*)d_in[16];
    const float* g2_b = (const float*)d_in[17];

    float* out = (float*)d_out;
    float* ws = (float*)d_ws;

    float* ppart = ws + WS_PPART;
    float* glob = ws + WS_GLOB;
    float* kvp = ws + WS_KVP;
    float* ksp = ws + WS_KSP;
    ushort* kvt = (ushort*)(ws + WS_KVT);
    ushort* wfp = (ushort*)(ws + WS_WFP);
    ushort* l1t = (ushort*)(ws + WS_L1T);
    ushort* l2t = (ushort*)(ws + WS_L2T);
    ushort* kwt = (ushort*)(ws + WS_KWT);
    ushort* vwt = (ushort*)(ws + WS_VWT);

    // big intermediates inside d_out (qattn overwrites everything at the end)
    ushort* t = (ushort*)out;                      // 32768x256 bf16
    ushort* fre = (ushort*)(out + 4194304);        // 32768x256 bf16
    ushort* Km = (ushort*)(out + 8388608);         // 32768x256 bf16
    ushort* Vn = (ushort*)(out + 12582912);        // 32768x256 bf16

    k_prep<<<1792, 256, 0, stream>>>(l1_w, l2_w, k_w, v_w, mh, q_w, key,
                                     l1t, l2t, kwt, vwt, wfp, ppart);
    k_glob2<<<1, 256, 0, stream>>>(ppart, g1_w, g1_b, g2_w, g2_b, glob);

    // t = relu(s @ l1_w + l1_b)            (s gathered from key)
    gemm_bf<1, 0><<<512, 256, 0, stream>>>(key, l1t, l1_b, t, nullptr, nullptr);
    // fre = sigmoid(t @ l2_w + l2_b + glob) * high + low
    gemm_bf<0, 1><<<512, 256, 0, stream>>>(t, l2t, l2_b, fre, glob, key);
    // Km = elu(fre @ k_w + k_b) + 1        (bf16 out)
    gemm_bf<0, 4><<<512, 256, 0, stream>>>(fre, kwt, k_b, Km, nullptr, nullptr);
    // Vn = fre @ v_w + v_b                 (bf16 out, /16384 folded away)
    gemm_bf<0, 5><<<512, 256, 0, stream>>>(fre, vwt, v_b, Vn, nullptr, nullptr);

    k_kv_part<<<512, 256, 0, stream>>>(Km, Vn, kvp, ksp);
    k_kv_reduce<<<16, 256, 0, stream>>>(kvp, ksp, kvt);

    k_qattn_mfma<<<1024, 512, 0, stream>>>(query, wfp, q_b, kvt, out);
}

// Round 14
// 259.763 us; speedup vs baseline: 1.0563x; 1.0563x over previous
//
#include <hip/hip_runtime.h>
#include <math.h>

// Problem constants
#define BB 2

// ws layout (float offsets)
#define WS_PPART 0         // 2*128*256 pool partials
#define WS_GLOB  66048     // 2*256
#define WS_KVP   66560     // 16*32*1024 KV partials
#define WS_KSP   590848    // 16*32*32 Ksum partials
#define WS_KVT   607232    // bf16 KV_aug: 16*48*32 ushort
#define WS_WFP   619520    // bf16 Wf pre-tiled [16][256][32]: 131072 ushort
#define WS_L1T   685056    // bf16 l1 pre-tiled: 2*8*128*32 ushort
#define WS_L2T   717824
#define WS_KWT   750592
#define WS_VWT   783360

typedef __attribute__((ext_vector_type(8))) short short8v;
typedef __attribute__((ext_vector_type(4))) float f32x4;

__device__ __forceinline__ ushort f2bf(float x) {
    union { float f; unsigned int u; } v; v.f = x;
    unsigned int u = v.u;
    unsigned int r = (u + 0x7fffu + ((u >> 16) & 1u)) >> 16;
    return (ushort)r;
}

__device__ __forceinline__ float bf2f(ushort x) {
    union { float f; unsigned int u; } v;
    v.u = ((unsigned int)x) << 16;
    return v.f;
}

// packed f32x2 -> bf16x2 (RNE), 1 VALU op
__device__ __forceinline__ unsigned int cvtpk(float lo, float hi) {
    unsigned int d;
    asm("v_cvt_pk_bf16_f32 %0, %1, %2" : "=v"(d) : "v"(lo), "v"(hi));
    return d;
}

// async global->LDS, 16B per lane; LDS dest is wave-uniform base (+lane*16 by HW)
__device__ __forceinline__ void gload16(const void* g, void* l) {
    __builtin_amdgcn_global_load_lds(
        (const __attribute__((address_space(1))) unsigned int*)g,
        (__attribute__((address_space(3))) unsigned int*)l, 16, 0, 0);
}

// ---------------- merged prep: weight tiling + Wf fuse + pool partials (R7-exact) ----------------
__global__ __launch_bounds__(256) void k_prep(const float* __restrict__ l1w, const float* __restrict__ l2w,
                                              const float* __restrict__ kw, const float* __restrict__ vw,
                                              const float* __restrict__ mh, const float* __restrict__ qw,
                                              const float* __restrict__ key,
                                              ushort* __restrict__ t0, ushort* __restrict__ t1,
                                              ushort* __restrict__ t2, ushort* __restrict__ t3,
                                              ushort* __restrict__ wfp, float* __restrict__ ppart) {
    int blk = blockIdx.x, t = threadIdx.x;
    if (blk < 1024) {
        int mat = blk >> 8, k = blk & 255, n = t;
        const float* w = mat == 0 ? l1w : mat == 1 ? l2w : mat == 2 ? kw : vw;
        ushort* o = mat == 0 ? t0 : mat == 1 ? t1 : mat == 2 ? t2 : t3;
        o[(((size_t)(n >> 7) * 8 + (k >> 5)) * 128 + (n & 127)) * 32 + (k & 31)] = f2bf(w[k * 256 + n]);
    } else if (blk < 1536) {
        __shared__ float mr[256];
        int g = blk - 1024;
        mr[t] = mh[g * 256 + t];
        __syncthreads();
        float acc = 0.f;
        for (int k = 0; k < 256; k++) acc += mr[k] * qw[k * 256 + t];
        wfp[(((size_t)(g >> 5) * 256 + t) * 32 + (g & 31))] = f2bf(acc);
    } else {
        int p = blk - 1536;
        int b = p >> 7, ci = p & 127;
        float acc = 0.f;
        for (int q = 0; q < 128; q++) {
            size_t idx = ((size_t)b * 65536 + (size_t)(2 * ci + 1) * 256 + (2 * q + 1)) * 256 + t;
            acc += key[idx];
        }
        ppart[(size_t)p * 256 + t] = acc;
    }
}

// ---------------- pool reduce + glob (single block, R7-exact) ----------------
__global__ __launch_bounds__(256) void k_glob2(const float* __restrict__ ppart,
                                               const float* __restrict__ g1w,
                                               const float* __restrict__ g1b,
                                               const float* __restrict__ g2w,
                                               const float* __restrict__ g2b,
                                               float* __restrict__ glob) {
    __shared__ float pl[256], hid[256];
    int t = threadIdx.x;
    for (int b = 0; b < BB; b++) {
        float s = 0.f;
        for (int p = 0; p < 128; p++) s += ppart[((size_t)b * 128 + p) * 256 + t];
        pl[t] = s * (2.f / 16384.f);
        __syncthreads();
        float acc = g1b[t];
        for (int k = 0; k < 256; k++) acc += pl[k] * g1w[k * 256 + t];
        hid[t] = fmaxf(acc, 0.f);
        __syncthreads();
        float a2 = g2b[t];
        for (int k = 0; k < 256; k++) a2 += hid[k] * g2w[k * 256 + t];
        glob[b * 256 + t] = a2;
        __syncthreads();
    }
}

// ---------------- bf16 MFMA mid GEMM: 128x128 tile, K=256, M=32768 (R4/R7-proven) ----------------
// AMODE 0: A = bf16 rows.  AMODE 1: A gathered from key (x2 -> bf16).
// EPI 0: relu->bf16   EPI 1: fre epilogue->bf16
template <int AMODE, int EPI>
__global__ __launch_bounds__(256) void gemm_bf(const void* __restrict__ Asrc_,
                                               const ushort* __restrict__ Wt,
                                               const float* __restrict__ bias,
                                               void* __restrict__ Outp,
                                               const float* __restrict__ glob,
                                               const float* __restrict__ key) {
    __shared__ __align__(16) ushort smem[8192];   // As 8KB | Bs 8KB
    ushort* As = smem;
    ushort* Bs = smem + 4096;

    const int tid = threadIdx.x;
    const int lane = tid & 63;
    const int w = tid >> 6;
    const int wrow = w >> 1, wcol = w & 1;
    const int bx = blockIdx.x & 1;
    const int by = blockIdx.x >> 1;
    const int r0 = by * 128, n0 = bx * 128;
    const int l15 = lane & 15, l4 = lane >> 4;

    const int loff = lane * 16;
    char* ldsB0 = (char*)Bs + w * 2048;
    char* ldsB1 = (char*)Bs + w * 2048 + 1024;
    const int rowA0 = w * 32 + (lane >> 2);
    const int kbA = (lane & 3) * 16;
    char* ldsA0 = (char*)As + w * 2048;
    char* ldsA1 = (char*)As + w * 2048 + 1024;
    const int srow = tid >> 1, shalf = tid & 1;
    size_t agbase = 0;
    if constexpr (AMODE == 1) {
        int r = r0 + srow;
        int b = r >> 14, rr = r & 16383;
        int ii = rr >> 7, jj = rr & 127;
        agbase = ((size_t)b * 65536 + (size_t)(2 * ii + 1) * 256 + (2 * jj + 1)) * 256 + shalf * 16;
    }

    f32x4 acc[4][4];
#pragma unroll
    for (int i = 0; i < 4; i++)
#pragma unroll
        for (int j = 0; j < 4; j++) acc[i][j] = (f32x4){0.f, 0.f, 0.f, 0.f};

    for (int ks = 0; ks < 8; ks++) {
        const char* btile = (const char*)Wt + (size_t)(bx * 8 + ks) * 8192;
        gload16(btile + w * 2048 + loff, ldsB0);
        gload16(btile + w * 2048 + 1024 + loff, ldsB1);
        if constexpr (AMODE == 0) {
            const char* ab = (const char*)Asrc_;
            gload16(ab + (size_t)(r0 + rowA0) * 512 + ks * 64 + kbA, ldsA0);
            gload16(ab + (size_t)(r0 + rowA0 + 16) * 512 + ks * 64 + kbA, ldsA1);
        } else {
            const float* kf = (const float*)Asrc_;
            float4 f0 = *(const float4*)(kf + agbase + (size_t)ks * 32);
            float4 f1 = *(const float4*)(kf + agbase + (size_t)ks * 32 + 4);
            float4 f2 = *(const float4*)(kf + agbase + (size_t)ks * 32 + 8);
            float4 f3 = *(const float4*)(kf + agbase + (size_t)ks * 32 + 12);
            uint4 lo = {cvtpk(f0.x * 2.f, f0.y * 2.f), cvtpk(f0.z * 2.f, f0.w * 2.f),
                        cvtpk(f1.x * 2.f, f1.y * 2.f), cvtpk(f1.z * 2.f, f1.w * 2.f)};
            uint4 hi = {cvtpk(f2.x * 2.f, f2.y * 2.f), cvtpk(f2.z * 2.f, f2.w * 2.f),
                        cvtpk(f3.x * 2.f, f3.y * 2.f), cvtpk(f3.z * 2.f, f3.w * 2.f)};
            *(uint4*)((char*)As + srow * 64 + shalf * 32) = lo;
            *(uint4*)((char*)As + srow * 64 + shalf * 32 + 16) = hi;
        }
        __syncthreads();

        short8v a[4], bfr[4];
#pragma unroll
        for (int m = 0; m < 4; m++)
            a[m] = *(const short8v*)((const char*)As + (wrow * 64 + m * 16 + l15) * 64 + l4 * 16);
#pragma unroll
        for (int n = 0; n < 4; n++)
            bfr[n] = *(const short8v*)((const char*)Bs + (wcol * 64 + n * 16 + l15) * 64 + l4 * 16);
#pragma unroll
        for (int m = 0; m < 4; m++)
#pragma unroll
            for (int n = 0; n < 4; n++)
                acc[m][n] = __builtin_amdgcn_mfma_f32_16x16x32_bf16(a[m], bfr[n], acc[m][n], 0, 0, 0);
        __syncthreads();
    }

    const int b = r0 >> 14;
    float bv[4], gv[4];
#pragma unroll
    for (int n = 0; n < 4; n++) {
        int c = n0 + wcol * 64 + n * 16 + l15;
        bv[n] = bias[c];
        if constexpr (EPI == 1) gv[n] = glob[b * 256 + c];
    }
#pragma unroll
    for (int m = 0; m < 4; m++) {
#pragma unroll
        for (int n = 0; n < 4; n++) {
            int c = n0 + wcol * 64 + n * 16 + l15;
#pragma unroll
            for (int r = 0; r < 4; r++) {
                int row = wrow * 64 + m * 16 + l4 * 4 + r;
                int R = r0 + row;
                float x = acc[m][n][r] + bv[n];
                if constexpr (EPI == 0) {
                    ((ushort*)Outp)[(size_t)R * 256 + c] = f2bf(fmaxf(x, 0.f));
                } else {
                    int rr = R & 16383;
                    int ii = rr >> 7, jj = rr & 127;
                    size_t kb = ((size_t)b * 65536 + (size_t)(2 * ii) * 256 + 2 * jj) * 256 + c;
                    float ka = key[kb];
                    float kb2 = key[kb + 256];
                    float kc2 = key[kb + 65536];
                    float kd2 = key[kb + 65536 + 256];
                    float low = 0.5f * (ka + kb2 + kc2 + kd2);
                    float high = 0.5f * (3.f * kd2 - ka - kb2 - kc2);
                    float wei = 1.f / (1.f + __expf(-(x + gv[n])));
                    ((ushort*)Outp)[(size_t)R * 256 + c] = f2bf(wei * high + low);
                }
            }
        }
    }
}

// ---------------- batched K/V GEMM: 1024 blocks; blocks 0..511 -> Km (elu+1), 512..1023 -> Vn ----------------
// Per-block structure identical to gemm_bf<0,*> (same LDS/VGPR); one launch instead of two.
__global__ __launch_bounds__(256) void gemm_bf34(const ushort* __restrict__ Afre,
                                                 const ushort* __restrict__ kwt,
                                                 const ushort* __restrict__ vwt,
                                                 const float* __restrict__ kbias,
                                                 const float* __restrict__ vbias,
                                                 ushort* __restrict__ Km,
                                                 ushort* __restrict__ Vn) {
    __shared__ __align__(16) ushort smem[8192];   // As 8KB | Bs 8KB
    ushort* As = smem;
    ushort* Bs = smem + 4096;

    const int isV = blockIdx.x >= 512;
    const int blk = blockIdx.x & 511;
    const ushort* Wt = isV ? vwt : kwt;
    const float* bias = isV ? vbias : kbias;
    ushort* Outp = isV ? Vn : Km;

    const int tid = threadIdx.x;
    const int lane = tid & 63;
    const int w = tid >> 6;
    const int wrow = w >> 1, wcol = w & 1;
    const int bx = blk & 1;
    const int by = blk >> 1;
    const int r0 = by * 128, n0 = bx * 128;
    const int l15 = lane & 15, l4 = lane >> 4;

    const int loff = lane * 16;
    char* ldsB0 = (char*)Bs + w * 2048;
    char* ldsB1 = (char*)Bs + w * 2048 + 1024;
    const int rowA0 = w * 32 + (lane >> 2);
    const int kbA = (lane & 3) * 16;
    char* ldsA0 = (char*)As + w * 2048;
    char* ldsA1 = (char*)As + w * 2048 + 1024;

    f32x4 acc[4][4];
#pragma unroll
    for (int i = 0; i < 4; i++)
#pragma unroll
        for (int j = 0; j < 4; j++) acc[i][j] = (f32x4){0.f, 0.f, 0.f, 0.f};

    for (int ks = 0; ks < 8; ks++) {
        const char* btile = (const char*)Wt + (size_t)(bx * 8 + ks) * 8192;
        gload16(btile + w * 2048 + loff, ldsB0);
        gload16(btile + w * 2048 + 1024 + loff, ldsB1);
        const char* ab = (const char*)Afre;
        gload16(ab + (size_t)(r0 + rowA0) * 512 + ks * 64 + kbA, ldsA0);
        gload16(ab + (size_t)(r0 + rowA0 + 16) * 512 + ks * 64 + kbA, ldsA1);
        __syncthreads();

        short8v a[4], bfr[4];
#pragma unroll
        for (int m = 0; m < 4; m++)
            a[m] = *(const short8v*)((const char*)As + (wrow * 64 + m * 16 + l15) * 64 + l4 * 16);
#pragma unroll
        for (int n = 0; n < 4; n++)
            bfr[n] = *(const short8v*)((const char*)Bs + (wcol * 64 + n * 16 + l15) * 64 + l4 * 16);
#pragma unroll
        for (int m = 0; m < 4; m++)
#pragma unroll
            for (int n = 0; n < 4; n++)
                acc[m][n] = __builtin_amdgcn_mfma_f32_16x16x32_bf16(a[m], bfr[n], acc[m][n], 0, 0, 0);
        __syncthreads();
    }

    float bv[4];
#pragma unroll
    for (int n = 0; n < 4; n++) bv[n] = bias[n0 + wcol * 64 + n * 16 + l15];
#pragma unroll
    for (int m = 0; m < 4; m++) {
#pragma unroll
        for (int n = 0; n < 4; n++) {
            int c = n0 + wcol * 64 + n * 16 + l15;
#pragma unroll
            for (int r = 0; r < 4; r++) {
                int R = r0 + wrow * 64 + m * 16 + l4 * 4 + r;
                float x = acc[m][n][r] + bv[n];
                // block-uniform branch: K gets elu+1, V identity
                float o = isV ? x : ((x > 0.f) ? x + 1.f : __expf(x));
                Outp[(size_t)R * 256 + c] = f2bf(o);
            }
        }
    }
}

// ---------------- KV partials (bf16 in, R7-exact 8-row stages) ----------------
__global__ __launch_bounds__(256) void k_kv_part(const ushort* __restrict__ Km,
                                                 const ushort* __restrict__ Vn,
                                                 float* __restrict__ kvp,
                                                 float* __restrict__ ksp) {
    __shared__ float Kl[8][33];
    __shared__ float Vl[8][33];
    int t = threadIdx.x;
    int c = blockIdx.x & 31, h = (blockIdx.x >> 5) & 7, b = blockIdx.x >> 8;
    int d = t >> 3, vq = (t & 7) * 4;
    int lr = t >> 5, lc = t & 31;
    float acc0 = 0, acc1 = 0, acc2 = 0, acc3 = 0, ks = 0;
    size_t rowbase = (size_t)b * 16384 + (size_t)c * 512;
    for (int s0 = 0; s0 < 512; s0 += 8) {
        size_t idx = (rowbase + s0 + lr) * 256 + h * 32 + lc;
        Kl[lr][lc] = bf2f(Km[idx]);
        Vl[lr][lc] = bf2f(Vn[idx]);
        __syncthreads();
#pragma unroll
        for (int rr = 0; rr < 8; rr++) {
            float kd = Kl[rr][d];
            acc0 += kd * Vl[rr][vq];
            acc1 += kd * Vl[rr][vq + 1];
            acc2 += kd * Vl[rr][vq + 2];
            acc3 += kd * Vl[rr][vq + 3];
            ks += kd;
        }
        __syncthreads();
    }
    size_t ob = ((size_t)(b * 8 + h) * 32 + c) * 1024 + d * 32 + vq;
    kvp[ob] = acc0; kvp[ob + 1] = acc1; kvp[ob + 2] = acc2; kvp[ob + 3] = acc3;
    if ((t & 7) == 0) ksp[((b * 8 + h) * 32 + c) * 32 + d] = ks;
}

// ---------------- KV reduce -> bf16 augmented B^T: KVt[bh][48][32] (R7-exact) ----------------
__global__ __launch_bounds__(256) void k_kv_reduce(const float* __restrict__ kvp,
                                                   const float* __restrict__ ksp,
                                                   ushort* __restrict__ kvt) {
    int bh = blockIdx.x, t = threadIdx.x;
    for (int e = t; e < 1024; e += 256) {
        float s = 0.f;
        for (int cc = 0; cc < 32; cc++) s += kvp[((size_t)bh * 32 + cc) * 1024 + e];
        int d = e >> 5, v = e & 31;
        kvt[((size_t)bh * 48 + v) * 32 + d] = f2bf(s);
    }
    if (t < 32) {
        float s = 0.f;
        for (int cc = 0; cc < 32; cc++) s += ksp[(bh * 32 + cc) * 32 + t];
        kvt[((size_t)bh * 48 + 32) * 32 + t] = f2bf(s);
    }
    for (int z = t; z < 480; z += 256) kvt[(size_t)bh * 48 * 32 + 33 * 32 + z] = 0;
}

// ---------------- MFMA q-GEMM (BM=128, BN=256, BK=32), 2-phase pipelined (R7 BEST, byte-exact) ----------------
__global__ __launch_bounds__(512, 4) void k_qattn_mfma(const float* __restrict__ query,
                                                       const ushort* __restrict__ wfp,
                                                       const float* __restrict__ qb,
                                                       const ushort* __restrict__ kvt,
                                                       float* __restrict__ Out) {
    __shared__ __align__(16) char smem[65536];
    char* As0 = smem;                // [128][32] f32 (16KB)
    char* As1 = smem + 16384;
    char* Bs0 = smem + 32768;        // [256][32] bf16 (16KB)
    char* Bs1 = smem + 49152;

    const int tid = threadIdx.x;
    const int lane = tid & 63;
    const int wid = tid >> 6;            // 0..7
    const int wrow = wid >> 2, wcol = wid & 3;
    const int R0 = blockIdx.x * 128;
    const int l15 = lane & 15, l4 = lane >> 4;

    const int arow0 = wid * 16 + (lane >> 3);
    const int achunk = (lane & 7) ^ (lane >> 3);
    const float* aga = query + (size_t)(R0 + arow0) * 512 + achunk * 4;
    const int wb = wid * 2048;
    const int bglo = wb + lane * 16;

    f32x4 acc[4][4];
#pragma unroll
    for (int i = 0; i < 4; i++)
#pragma unroll
        for (int j = 0; j < 4; j++) acc[i][j] = (f32x4){0.f, 0.f, 0.f, 0.f};

#define QSTAGE(dA, dB, kss)                                                     \
    do {                                                                        \
        const float* ga_ = aga + (size_t)(kss) * 32;                            \
        gload16(ga_, (dA) + wb);                                                \
        gload16(ga_ + 8 * 512, (dA) + wb + 1024);                               \
        const char* pan_ = (const char*)wfp + (size_t)(kss) * 16384 + bglo;     \
        gload16(pan_, (dB) + wb);                                               \
        gload16(pan_ + 1024, (dB) + wb + 1024);                                 \
    } while (0)

    QSTAGE(As0, Bs0, 0);
    asm volatile("s_waitcnt vmcnt(0)" ::: "memory");
    __builtin_amdgcn_s_barrier();
    __builtin_amdgcn_sched_barrier(0);

    for (int ks = 0; ks < 16; ks++) {
        const char* bA = (ks & 1) ? As1 : As0;
        const char* bB = (ks & 1) ? Bs1 : Bs0;
        char* nA = (ks & 1) ? As0 : As1;
        char* nB = (ks & 1) ? Bs0 : Bs1;
        if (ks < 15) QSTAGE(nA, nB, ks + 1);

        short8v bfr[4];
#pragma unroll
        for (int n = 0; n < 4; n++)
            bfr[n] = *(const short8v*)(bB + (wcol * 64 + n * 16 + l15) * 64 + l4 * 16);
#pragma unroll
        for (int m = 0; m < 4; m++) {
            int row = wrow * 64 + m * 16 + l15;
            int j0 = (l4 * 2) ^ (l15 & 7);
            const char* rp = bA + row * 128;
            f32x4 lo = *(const f32x4*)(rp + j0 * 16);
            f32x4 hi = *(const f32x4*)(rp + (j0 ^ 1) * 16);
            union { uint4 u; short8v s; } av;
            av.u = (uint4){cvtpk(lo.x, lo.y), cvtpk(lo.z, lo.w),
                           cvtpk(hi.x, hi.y), cvtpk(hi.z, hi.w)};
#pragma unroll
            for (int n = 0; n < 4; n++)
                acc[m][n] = __builtin_amdgcn_mfma_f32_16x16x32_bf16(av.s, bfr[n], acc[m][n], 0, 0, 0);
        }

        if (ks < 15) {
            asm volatile("s_waitcnt vmcnt(0)" ::: "memory");
            __builtin_amdgcn_s_barrier();
            __builtin_amdgcn_sched_barrier(0);
        }
    }
#undef QSTAGE

    __syncthreads();

    float qbv[4];
#pragma unroll
    for (int n = 0; n < 4; n++) qbv[n] = qb[wcol * 64 + n * 16 + l15];
#pragma unroll
    for (int m = 0; m < 4; m++) {
#pragma unroll
        for (int n = 0; n < 4; n++) {
#pragma unroll
            for (int r = 0; r < 4; r++) {
                int rl = m * 16 + l4 * 4 + r;
                int cl = n * 16 + l15;
                float x = acc[m][n][r] + qbv[n];
                float q = x > 0.f ? x + 1.f : __expf(x);
                int byte = wid * 8192 + ((rl * 128 + cl * 2) ^ ((rl & 7) << 4));
                *(ushort*)(smem + byte) = f2bf(q);
            }
        }
    }
    __syncthreads();

    const int bb = R0 >> 16;
#pragma unroll
    for (int hi = 0; hi < 2; hi++) {
        int h = wcol * 2 + hi;
        int bh = bb * 8 + h;
        const ushort* kb = kvt + (size_t)bh * 48 * 32;
        short8v bk0 = *(const short8v*)(kb + (0 * 16 + l15) * 32 + l4 * 8);
        short8v bk1 = *(const short8v*)(kb + (1 * 16 + l15) * 32 + l4 * 8);
        short8v bkz = *(const short8v*)(kb + (2 * 16 + l15) * 32 + l4 * 8);
#pragma unroll
        for (int m = 0; m < 4; m++) {
            int rl = m * 16 + l15;
            int byte = wid * 8192 + ((rl * 128 + hi * 64 + l4 * 16) ^ ((rl & 7) << 4));
            short8v aq = *(const short8v*)(smem + byte);
            f32x4 zero = (f32x4){0.f, 0.f, 0.f, 0.f};
            f32x4 o0 = __builtin_amdgcn_mfma_f32_16x16x32_bf16(aq, bk0, zero, 0, 0, 0);
            f32x4 o1 = __builtin_amdgcn_mfma_f32_16x16x32_bf16(aq, bk1, zero, 0, 0, 0);
            f32x4 oz = __builtin_amdgcn_mfma_f32_16x16x32_bf16(aq, bkz, zero, 0, 0, 0);
#pragma unroll
            for (int r = 0; r < 4; r++) {
                float z = __shfl(oz[r], (lane & 48));
                float sc = 1.f / (z + 1e-6f);
                int grow = R0 + wrow * 64 + m * 16 + l4 * 4 + r;
                int gcol = wcol * 64 + hi * 32 + l15;
                Out[(size_t)grow * 256 + gcol] = o0[r] * sc;
                Out[(size_t)grow * 256 + gcol + 16] = o1[r] * sc;
            }
        }
    }
}

extern "C" void kernel_launch(void* const* d_in, const int* in_sizes, int n_in,
                              void* d_out, int out_size, void* d_ws, size_t ws_size,
                              hipStream_t stream) {
    const float* query = (const float*)d_in[0];
    const float* key = (const float*)d_in[1];
    // d_in[2] = value: only its shape is used by the reference — never read.
    const float* mh = (const float*)d_in[3];
    const float* q_w = (const float*)d_in[4];
    const float* q_b = (const float*)d_in[5];
    const float* k_w = (const float*)d_in[6];
    const float* k_b = (const float*)d_in[7];
    const float* v_w = (const float*)d_in[8];
    const float* v_b = (const float*)d_in[9];
    const float* l1_w = (const float*)d_in[10];
    const float* l1_b = (const float*)d_in[11];
    const float* l2_w = (const float*)d_in[12];
    const float* l2_b = (const float*)d_in[13];
    const float* g1_w = (const float*)d_in[14];
    const float* g1_b = (const float*)d_in[15];
    const float* g2_w = (const float*)d_in[16];
    const float* g2_b = (const float*)d_in[17];

    float* out = (float*)d_out;
    float* ws = (float*)d_ws;

    float* ppart = ws + WS_PPART;
    float* glob = ws + WS_GLOB;
    float* kvp = ws + WS_KVP;
    float* ksp = ws + WS_KSP;
    ushort* kvt = (ushort*)(ws + WS_KVT);
    ushort* wfp = (ushort*)(ws + WS_WFP);
    ushort* l1t = (ushort*)(ws + WS_L1T);
    ushort* l2t = (ushort*)(ws + WS_L2T);
    ushort* kwt = (ushort*)(ws + WS_KWT);
    ushort* vwt = (ushort*)(ws + WS_VWT);

    // big intermediates inside d_out (qattn overwrites everything at the end)
    ushort* t = (ushort*)out;                      // 32768x256 bf16
    ushort* fre = (ushort*)(out + 4194304);        // 32768x256 bf16
    ushort* Km = (ushort*)(out + 8388608);         // 32768x256 bf16
    ushort* Vn = (ushort*)(out + 12582912);        // 32768x256 bf16

    k_prep<<<1792, 256, 0, stream>>>(l1_w, l2_w, k_w, v_w, mh, q_w, key,
                                     l1t, l2t, kwt, vwt, wfp, ppart);
    k_glob2<<<1, 256, 0, stream>>>(ppart, g1_w, g1_b, g2_w, g2_b, glob);

    // t = relu(s @ l1_w + l1_b)            (s gathered from key)
    gemm_bf<1, 0><<<512, 256, 0, stream>>>(key, l1t, l1_b, t, nullptr, nullptr);
    // fre = sigmoid(t @ l2_w + l2_b + glob) * high + low
    gemm_bf<0, 1><<<512, 256, 0, stream>>>(t, l2t, l2_b, fre, glob, key);
    // Km = elu(fre@k_w+k_b)+1  and  Vn = fre@v_w+v_b  in ONE batched launch
    gemm_bf34<<<1024, 256, 0, stream>>>(fre, kwt, vwt, k_b, v_b, Km, Vn);

    k_kv_part<<<512, 256, 0, stream>>>(Km, Vn, kvp, ksp);
    k_kv_reduce<<<16, 256, 0, stream>>>(kvp, ksp, kvt);

    k_qattn_mfma<<<1024, 512, 0, stream>>>(query, wfp, q_b, kvt, out);
}

// Round 15
// 252.881 us; speedup vs baseline: 1.0850x; 1.0272x over previous
//
#include <hip/hip_runtime.h>
#include <math.h>

// Problem constants
#define BB 2

// ws layout (float offsets)
#define WS_PPART 0         // 2*128*256 pool partials
#define WS_GLOB  66048     // 2*256
#define WS_KVP   66560     // 16*32*1024 KV partials
#define WS_KSP   590848    // 16*32*32 Ksum partials
#define WS_KVT   607232    // bf16 KV_aug: 16*48*32 ushort
#define WS_WFP   619520    // bf16 Wf pre-tiled [16][256][32]: 131072 ushort
#define WS_L1T   685056    // bf16 l1 pre-tiled: 2*8*128*32 ushort
#define WS_L2T   717824
#define WS_KWT   750592
#define WS_VWT   783360

typedef __attribute__((ext_vector_type(8))) short short8v;
typedef __attribute__((ext_vector_type(4))) float f32x4;

__device__ __forceinline__ ushort f2bf(float x) {
    union { float f; unsigned int u; } v; v.f = x;
    unsigned int u = v.u;
    unsigned int r = (u + 0x7fffu + ((u >> 16) & 1u)) >> 16;
    return (ushort)r;
}

__device__ __forceinline__ float bf2f(ushort x) {
    union { float f; unsigned int u; } v;
    v.u = ((unsigned int)x) << 16;
    return v.f;
}

// packed f32x2 -> bf16x2 (RNE), 1 VALU op
__device__ __forceinline__ unsigned int cvtpk(float lo, float hi) {
    unsigned int d;
    asm("v_cvt_pk_bf16_f32 %0, %1, %2" : "=v"(d) : "v"(lo), "v"(hi));
    return d;
}

// async global->LDS, 16B per lane; LDS dest is wave-uniform base (+lane*16 by HW)
__device__ __forceinline__ void gload16(const void* g, void* l) {
    __builtin_amdgcn_global_load_lds(
        (const __attribute__((address_space(1))) unsigned int*)g,
        (__attribute__((address_space(3))) unsigned int*)l, 16, 0, 0);
}

// ---------------- merged prep: weight tiling + Wf fuse + pool partials (R7-exact) ----------------
__global__ __launch_bounds__(256) void k_prep(const float* __restrict__ l1w, const float* __restrict__ l2w,
                                              const float* __restrict__ kw, const float* __restrict__ vw,
                                              const float* __restrict__ mh, const float* __restrict__ qw,
                                              const float* __restrict__ key,
                                              ushort* __restrict__ t0, ushort* __restrict__ t1,
                                              ushort* __restrict__ t2, ushort* __restrict__ t3,
                                              ushort* __restrict__ wfp, float* __restrict__ ppart) {
    int blk = blockIdx.x, t = threadIdx.x;
    if (blk < 1024) {
        int mat = blk >> 8, k = blk & 255, n = t;
        const float* w = mat == 0 ? l1w : mat == 1 ? l2w : mat == 2 ? kw : vw;
        ushort* o = mat == 0 ? t0 : mat == 1 ? t1 : mat == 2 ? t2 : t3;
        o[(((size_t)(n >> 7) * 8 + (k >> 5)) * 128 + (n & 127)) * 32 + (k & 31)] = f2bf(w[k * 256 + n]);
    } else if (blk < 1536) {
        __shared__ float mr[256];
        int g = blk - 1024;
        mr[t] = mh[g * 256 + t];
        __syncthreads();
        float acc = 0.f;
        for (int k = 0; k < 256; k++) acc += mr[k] * qw[k * 256 + t];
        wfp[(((size_t)(g >> 5) * 256 + t) * 32 + (g & 31))] = f2bf(acc);
    } else {
        int p = blk - 1536;
        int b = p >> 7, ci = p & 127;
        float acc = 0.f;
        for (int q = 0; q < 128; q++) {
            size_t idx = ((size_t)b * 65536 + (size_t)(2 * ci + 1) * 256 + (2 * q + 1)) * 256 + t;
            acc += key[idx];
        }
        ppart[(size_t)p * 256 + t] = acc;
    }
}

// ---------------- gemm1 (t = relu(s@l1+b), blocks 0..511) + glob2 body (block 512) ----------------
// Both depend only on k_prep; batching hides glob2's single-block serial time under gemm1.
__global__ __launch_bounds__(256) void gemm1_glob(const float* __restrict__ key,
                                                  const ushort* __restrict__ Wt,
                                                  const float* __restrict__ bias,
                                                  ushort* __restrict__ Outp,
                                                  const float* __restrict__ ppart,
                                                  const float* __restrict__ g1w,
                                                  const float* __restrict__ g1b,
                                                  const float* __restrict__ g2w,
                                                  const float* __restrict__ g2b,
                                                  float* __restrict__ glob) {
    __shared__ __align__(16) ushort smem[8192];   // gemm: As 8KB | Bs 8KB; glob block reuses as pl/hid

    const int tid = threadIdx.x;

    if (blockIdx.x == 512) {
        // ---- glob2 body (R7-exact math) ----
        float* pl = (float*)smem;          // 256 floats
        float* hid = (float*)smem + 256;   // 256 floats
        for (int b = 0; b < BB; b++) {
            float s = 0.f;
            for (int p = 0; p < 128; p++) s += ppart[((size_t)b * 128 + p) * 256 + tid];
            pl[tid] = s * (2.f / 16384.f);
            __syncthreads();
            float acc = g1b[tid];
            for (int k = 0; k < 256; k++) acc += pl[k] * g1w[k * 256 + tid];
            hid[tid] = fmaxf(acc, 0.f);
            __syncthreads();
            float a2 = g2b[tid];
            for (int k = 0; k < 256; k++) a2 += hid[k] * g2w[k * 256 + tid];
            glob[b * 256 + tid] = a2;
            __syncthreads();
        }
        return;
    }

    // ---- gemm_bf<1,0> body (R14-exact) ----
    ushort* As = smem;
    ushort* Bs = smem + 4096;

    const int lane = tid & 63;
    const int w = tid >> 6;
    const int wrow = w >> 1, wcol = w & 1;
    const int bx = blockIdx.x & 1;
    const int by = blockIdx.x >> 1;
    const int r0 = by * 128, n0 = bx * 128;
    const int l15 = lane & 15, l4 = lane >> 4;

    const int loff = lane * 16;
    char* ldsB0 = (char*)Bs + w * 2048;
    char* ldsB1 = (char*)Bs + w * 2048 + 1024;
    const int srow = tid >> 1, shalf = tid & 1;
    size_t agbase;
    {
        int r = r0 + srow;
        int b = r >> 14, rr = r & 16383;
        int ii = rr >> 7, jj = rr & 127;
        agbase = ((size_t)b * 65536 + (size_t)(2 * ii + 1) * 256 + (2 * jj + 1)) * 256 + shalf * 16;
    }

    f32x4 acc[4][4];
#pragma unroll
    for (int i = 0; i < 4; i++)
#pragma unroll
        for (int j = 0; j < 4; j++) acc[i][j] = (f32x4){0.f, 0.f, 0.f, 0.f};

    for (int ks = 0; ks < 8; ks++) {
        const char* btile = (const char*)Wt + (size_t)(bx * 8 + ks) * 8192;
        gload16(btile + w * 2048 + loff, ldsB0);
        gload16(btile + w * 2048 + 1024 + loff, ldsB1);
        {
            float4 f0 = *(const float4*)(key + agbase + (size_t)ks * 32);
            float4 f1 = *(const float4*)(key + agbase + (size_t)ks * 32 + 4);
            float4 f2 = *(const float4*)(key + agbase + (size_t)ks * 32 + 8);
            float4 f3 = *(const float4*)(key + agbase + (size_t)ks * 32 + 12);
            uint4 lo = {cvtpk(f0.x * 2.f, f0.y * 2.f), cvtpk(f0.z * 2.f, f0.w * 2.f),
                        cvtpk(f1.x * 2.f, f1.y * 2.f), cvtpk(f1.z * 2.f, f1.w * 2.f)};
            uint4 hi = {cvtpk(f2.x * 2.f, f2.y * 2.f), cvtpk(f2.z * 2.f, f2.w * 2.f),
                        cvtpk(f3.x * 2.f, f3.y * 2.f), cvtpk(f3.z * 2.f, f3.w * 2.f)};
            *(uint4*)((char*)As + srow * 64 + shalf * 32) = lo;
            *(uint4*)((char*)As + srow * 64 + shalf * 32 + 16) = hi;
        }
        __syncthreads();

        short8v a[4], bfr[4];
#pragma unroll
        for (int m = 0; m < 4; m++)
            a[m] = *(const short8v*)((const char*)As + (wrow * 64 + m * 16 + l15) * 64 + l4 * 16);
#pragma unroll
        for (int n = 0; n < 4; n++)
            bfr[n] = *(const short8v*)((const char*)Bs + (wcol * 64 + n * 16 + l15) * 64 + l4 * 16);
#pragma unroll
        for (int m = 0; m < 4; m++)
#pragma unroll
            for (int n = 0; n < 4; n++)
                acc[m][n] = __builtin_amdgcn_mfma_f32_16x16x32_bf16(a[m], bfr[n], acc[m][n], 0, 0, 0);
        __syncthreads();
    }

    float bv[4];
#pragma unroll
    for (int n = 0; n < 4; n++) bv[n] = bias[n0 + wcol * 64 + n * 16 + l15];
#pragma unroll
    for (int m = 0; m < 4; m++) {
#pragma unroll
        for (int n = 0; n < 4; n++) {
            int c = n0 + wcol * 64 + n * 16 + l15;
#pragma unroll
            for (int r = 0; r < 4; r++) {
                int R = r0 + wrow * 64 + m * 16 + l4 * 4 + r;
                float x = acc[m][n][r] + bv[n];
                Outp[(size_t)R * 256 + c] = f2bf(fmaxf(x, 0.f));
            }
        }
    }
}

// ---------------- bf16 MFMA mid GEMM (R14-exact, used for gemm2 only) ----------------
template <int AMODE, int EPI>
__global__ __launch_bounds__(256) void gemm_bf(const void* __restrict__ Asrc_,
                                               const ushort* __restrict__ Wt,
                                               const float* __restrict__ bias,
                                               void* __restrict__ Outp,
                                               const float* __restrict__ glob,
                                               const float* __restrict__ key) {
    __shared__ __align__(16) ushort smem[8192];   // As 8KB | Bs 8KB
    ushort* As = smem;
    ushort* Bs = smem + 4096;

    const int tid = threadIdx.x;
    const int lane = tid & 63;
    const int w = tid >> 6;
    const int wrow = w >> 1, wcol = w & 1;
    const int bx = blockIdx.x & 1;
    const int by = blockIdx.x >> 1;
    const int r0 = by * 128, n0 = bx * 128;
    const int l15 = lane & 15, l4 = lane >> 4;

    const int loff = lane * 16;
    char* ldsB0 = (char*)Bs + w * 2048;
    char* ldsB1 = (char*)Bs + w * 2048 + 1024;
    const int rowA0 = w * 32 + (lane >> 2);
    const int kbA = (lane & 3) * 16;
    char* ldsA0 = (char*)As + w * 2048;
    char* ldsA1 = (char*)As + w * 2048 + 1024;
    const int srow = tid >> 1, shalf = tid & 1;
    size_t agbase = 0;
    if constexpr (AMODE == 1) {
        int r = r0 + srow;
        int b = r >> 14, rr = r & 16383;
        int ii = rr >> 7, jj = rr & 127;
        agbase = ((size_t)b * 65536 + (size_t)(2 * ii + 1) * 256 + (2 * jj + 1)) * 256 + shalf * 16;
    }

    f32x4 acc[4][4];
#pragma unroll
    for (int i = 0; i < 4; i++)
#pragma unroll
        for (int j = 0; j < 4; j++) acc[i][j] = (f32x4){0.f, 0.f, 0.f, 0.f};

    for (int ks = 0; ks < 8; ks++) {
        const char* btile = (const char*)Wt + (size_t)(bx * 8 + ks) * 8192;
        gload16(btile + w * 2048 + loff, ldsB0);
        gload16(btile + w * 2048 + 1024 + loff, ldsB1);
        if constexpr (AMODE == 0) {
            const char* ab = (const char*)Asrc_;
            gload16(ab + (size_t)(r0 + rowA0) * 512 + ks * 64 + kbA, ldsA0);
            gload16(ab + (size_t)(r0 + rowA0 + 16) * 512 + ks * 64 + kbA, ldsA1);
        } else {
            const float* kf = (const float*)Asrc_;
            float4 f0 = *(const float4*)(kf + agbase + (size_t)ks * 32);
            float4 f1 = *(const float4*)(kf + agbase + (size_t)ks * 32 + 4);
            float4 f2 = *(const float4*)(kf + agbase + (size_t)ks * 32 + 8);
            float4 f3 = *(const float4*)(kf + agbase + (size_t)ks * 32 + 12);
            uint4 lo = {cvtpk(f0.x * 2.f, f0.y * 2.f), cvtpk(f0.z * 2.f, f0.w * 2.f),
                        cvtpk(f1.x * 2.f, f1.y * 2.f), cvtpk(f1.z * 2.f, f1.w * 2.f)};
            uint4 hi = {cvtpk(f2.x * 2.f, f2.y * 2.f), cvtpk(f2.z * 2.f, f2.w * 2.f),
                        cvtpk(f3.x * 2.f, f3.y * 2.f), cvtpk(f3.z * 2.f, f3.w * 2.f)};
            *(uint4*)((char*)As + srow * 64 + shalf * 32) = lo;
            *(uint4*)((char*)As + srow * 64 + shalf * 32 + 16) = hi;
        }
        __syncthreads();

        short8v a[4], bfr[4];
#pragma unroll
        for (int m = 0; m < 4; m++)
            a[m] = *(const short8v*)((const char*)As + (wrow * 64 + m * 16 + l15) * 64 + l4 * 16);
#pragma unroll
        for (int n = 0; n < 4; n++)
            bfr[n] = *(const short8v*)((const char*)Bs + (wcol * 64 + n * 16 + l15) * 64 + l4 * 16);
#pragma unroll
        for (int m = 0; m < 4; m++)
#pragma unroll
            for (int n = 0; n < 4; n++)
                acc[m][n] = __builtin_amdgcn_mfma_f32_16x16x32_bf16(a[m], bfr[n], acc[m][n], 0, 0, 0);
        __syncthreads();
    }

    const int b = r0 >> 14;
    float bv[4], gv[4];
#pragma unroll
    for (int n = 0; n < 4; n++) {
        int c = n0 + wcol * 64 + n * 16 + l15;
        bv[n] = bias[c];
        if constexpr (EPI == 1) gv[n] = glob[b * 256 + c];
    }
#pragma unroll
    for (int m = 0; m < 4; m++) {
#pragma unroll
        for (int n = 0; n < 4; n++) {
            int c = n0 + wcol * 64 + n * 16 + l15;
#pragma unroll
            for (int r = 0; r < 4; r++) {
                int row = wrow * 64 + m * 16 + l4 * 4 + r;
                int R = r0 + row;
                float x = acc[m][n][r] + bv[n];
                if constexpr (EPI == 0) {
                    ((ushort*)Outp)[(size_t)R * 256 + c] = f2bf(fmaxf(x, 0.f));
                } else {
                    int rr = R & 16383;
                    int ii = rr >> 7, jj = rr & 127;
                    size_t kb = ((size_t)b * 65536 + (size_t)(2 * ii) * 256 + 2 * jj) * 256 + c;
                    float ka = key[kb];
                    float kb2 = key[kb + 256];
                    float kc2 = key[kb + 65536];
                    float kd2 = key[kb + 65536 + 256];
                    float low = 0.5f * (ka + kb2 + kc2 + kd2);
                    float high = 0.5f * (3.f * kd2 - ka - kb2 - kc2);
                    float wei = 1.f / (1.f + __expf(-(x + gv[n])));
                    ((ushort*)Outp)[(size_t)R * 256 + c] = f2bf(wei * high + low);
                }
            }
        }
    }
}

// ---------------- batched K/V GEMM (R14-exact) ----------------
__global__ __launch_bounds__(256) void gemm_bf34(const ushort* __restrict__ Afre,
                                                 const ushort* __restrict__ kwt,
                                                 const ushort* __restrict__ vwt,
                                                 const float* __restrict__ kbias,
                                                 const float* __restrict__ vbias,
                                                 ushort* __restrict__ Km,
                                                 ushort* __restrict__ Vn) {
    __shared__ __align__(16) ushort smem[8192];   // As 8KB | Bs 8KB
    ushort* As = smem;
    ushort* Bs = smem + 4096;

    const int isV = blockIdx.x >= 512;
    const int blk = blockIdx.x & 511;
    const ushort* Wt = isV ? vwt : kwt;
    const float* bias = isV ? vbias : kbias;
    ushort* Outp = isV ? Vn : Km;

    const int tid = threadIdx.x;
    const int lane = tid & 63;
    const int w = tid >> 6;
    const int wrow = w >> 1, wcol = w & 1;
    const int bx = blk & 1;
    const int by = blk >> 1;
    const int r0 = by * 128, n0 = bx * 128;
    const int l15 = lane & 15, l4 = lane >> 4;

    const int loff = lane * 16;
    char* ldsB0 = (char*)Bs + w * 2048;
    char* ldsB1 = (char*)Bs + w * 2048 + 1024;
    const int rowA0 = w * 32 + (lane >> 2);
    const int kbA = (lane & 3) * 16;
    char* ldsA0 = (char*)As + w * 2048;
    char* ldsA1 = (char*)As + w * 2048 + 1024;

    f32x4 acc[4][4];
#pragma unroll
    for (int i = 0; i < 4; i++)
#pragma unroll
        for (int j = 0; j < 4; j++) acc[i][j] = (f32x4){0.f, 0.f, 0.f, 0.f};

    for (int ks = 0; ks < 8; ks++) {
        const char* btile = (const char*)Wt + (size_t)(bx * 8 + ks) * 8192;
        gload16(btile + w * 2048 + loff, ldsB0);
        gload16(btile + w * 2048 + 1024 + loff, ldsB1);
        const char* ab = (const char*)Afre;
        gload16(ab + (size_t)(r0 + rowA0) * 512 + ks * 64 + kbA, ldsA0);
        gload16(ab + (size_t)(r0 + rowA0 + 16) * 512 + ks * 64 + kbA, ldsA1);
        __syncthreads();

        short8v a[4], bfr[4];
#pragma unroll
        for (int m = 0; m < 4; m++)
            a[m] = *(const short8v*)((const char*)As + (wrow * 64 + m * 16 + l15) * 64 + l4 * 16);
#pragma unroll
        for (int n = 0; n < 4; n++)
            bfr[n] = *(const short8v*)((const char*)Bs + (wcol * 64 + n * 16 + l15) * 64 + l4 * 16);
#pragma unroll
        for (int m = 0; m < 4; m++)
#pragma unroll
            for (int n = 0; n < 4; n++)
                acc[m][n] = __builtin_amdgcn_mfma_f32_16x16x32_bf16(a[m], bfr[n], acc[m][n], 0, 0, 0);
        __syncthreads();
    }

    float bv[4];
#pragma unroll
    for (int n = 0; n < 4; n++) bv[n] = bias[n0 + wcol * 64 + n * 16 + l15];
#pragma unroll
    for (int m = 0; m < 4; m++) {
#pragma unroll
        for (int n = 0; n < 4; n++) {
            int c = n0 + wcol * 64 + n * 16 + l15;
#pragma unroll
            for (int r = 0; r < 4; r++) {
                int R = r0 + wrow * 64 + m * 16 + l4 * 4 + r;
                float x = acc[m][n][r] + bv[n];
                float o = isV ? x : ((x > 0.f) ? x + 1.f : __expf(x));
                Outp[(size_t)R * 256 + c] = f2bf(o);
            }
        }
    }
}

// ---------------- KV partials (bf16 in, R7-exact 8-row stages) ----------------
__global__ __launch_bounds__(256) void k_kv_part(const ushort* __restrict__ Km,
                                                 const ushort* __restrict__ Vn,
                                                 float* __restrict__ kvp,
                                                 float* __restrict__ ksp) {
    __shared__ float Kl[8][33];
    __shared__ float Vl[8][33];
    int t = threadIdx.x;
    int c = blockIdx.x & 31, h = (blockIdx.x >> 5) & 7, b = blockIdx.x >> 8;
    int d = t >> 3, vq = (t & 7) * 4;
    int lr = t >> 5, lc = t & 31;
    float acc0 = 0, acc1 = 0, acc2 = 0, acc3 = 0, ks = 0;
    size_t rowbase = (size_t)b * 16384 + (size_t)c * 512;
    for (int s0 = 0; s0 < 512; s0 += 8) {
        size_t idx = (rowbase + s0 + lr) * 256 + h * 32 + lc;
        Kl[lr][lc] = bf2f(Km[idx]);
        Vl[lr][lc] = bf2f(Vn[idx]);
        __syncthreads();
#pragma unroll
        for (int rr = 0; rr < 8; rr++) {
            float kd = Kl[rr][d];
            acc0 += kd * Vl[rr][vq];
            acc1 += kd * Vl[rr][vq + 1];
            acc2 += kd * Vl[rr][vq + 2];
            acc3 += kd * Vl[rr][vq + 3];
            ks += kd;
        }
        __syncthreads();
    }
    size_t ob = ((size_t)(b * 8 + h) * 32 + c) * 1024 + d * 32 + vq;
    kvp[ob] = acc0; kvp[ob + 1] = acc1; kvp[ob + 2] = acc2; kvp[ob + 3] = acc3;
    if ((t & 7) == 0) ksp[((b * 8 + h) * 32 + c) * 32 + d] = ks;
}

// ---------------- KV reduce -> bf16 augmented B^T: KVt[bh][48][32] (R7-exact) ----------------
__global__ __launch_bounds__(256) void k_kv_reduce(const float* __restrict__ kvp,
                                                   const float* __restrict__ ksp,
                                                   ushort* __restrict__ kvt) {
    int bh = blockIdx.x, t = threadIdx.x;
    for (int e = t; e < 1024; e += 256) {
        float s = 0.f;
        for (int cc = 0; cc < 32; cc++) s += kvp[((size_t)bh * 32 + cc) * 1024 + e];
        int d = e >> 5, v = e & 31;
        kvt[((size_t)bh * 48 + v) * 32 + d] = f2bf(s);
    }
    if (t < 32) {
        float s = 0.f;
        for (int cc = 0; cc < 32; cc++) s += ksp[(bh * 32 + cc) * 32 + t];
        kvt[((size_t)bh * 48 + 32) * 32 + t] = f2bf(s);
    }
    for (int z = t; z < 480; z += 256) kvt[(size_t)bh * 48 * 32 + 33 * 32 + z] = 0;
}

// ---------------- MFMA q-GEMM (BM=128, BN=256, BK=32), 2-phase pipelined (R7 BEST, byte-exact) ----------------
__global__ __launch_bounds__(512, 4) void k_qattn_mfma(const float* __restrict__ query,
                                                       const ushort* __restrict__ wfp,
                                                       const float* __restrict__ qb,
                                                       const ushort* __restrict__ kvt,
                                                       float* __restrict__ Out) {
    __shared__ __align__(16) char smem[65536];
    char* As0 = smem;                // [128][32] f32 (16KB)
    char* As1 = smem + 16384;
    char* Bs0 = smem + 32768;        // [256][32] bf16 (16KB)
    char* Bs1 = smem + 49152;

    const int tid = threadIdx.x;
    const int lane = tid & 63;
    const int wid = tid >> 6;            // 0..7
    const int wrow = wid >> 2, wcol = wid & 3;
    const int R0 = blockIdx.x * 128;
    const int l15 = lane & 15, l4 = lane >> 4;

    const int arow0 = wid * 16 + (lane >> 3);
    const int achunk = (lane & 7) ^ (lane >> 3);
    const float* aga = query + (size_t)(R0 + arow0) * 512 + achunk * 4;
    const int wb = wid * 2048;
    const int bglo = wb + lane * 16;

    f32x4 acc[4][4];
#pragma unroll
    for (int i = 0; i < 4; i++)
#pragma unroll
        for (int j = 0; j < 4; j++) acc[i][j] = (f32x4){0.f, 0.f, 0.f, 0.f};

#define QSTAGE(dA, dB, kss)                                                     \
    do {                                                                        \
        const float* ga_ = aga + (size_t)(kss) * 32;                            \
        gload16(ga_, (dA) + wb);                                                \
        gload16(ga_ + 8 * 512, (dA) + wb + 1024);                               \
        const char* pan_ = (const char*)wfp + (size_t)(kss) * 16384 + bglo;     \
        gload16(pan_, (dB) + wb);                                               \
        gload16(pan_ + 1024, (dB) + wb + 1024);                                 \
    } while (0)

    QSTAGE(As0, Bs0, 0);
    asm volatile("s_waitcnt vmcnt(0)" ::: "memory");
    __builtin_amdgcn_s_barrier();
    __builtin_amdgcn_sched_barrier(0);

    for (int ks = 0; ks < 16; ks++) {
        const char* bA = (ks & 1) ? As1 : As0;
        const char* bB = (ks & 1) ? Bs1 : Bs0;
        char* nA = (ks & 1) ? As0 : As1;
        char* nB = (ks & 1) ? Bs0 : Bs1;
        if (ks < 15) QSTAGE(nA, nB, ks + 1);

        short8v bfr[4];
#pragma unroll
        for (int n = 0; n < 4; n++)
            bfr[n] = *(const short8v*)(bB + (wcol * 64 + n * 16 + l15) * 64 + l4 * 16);
#pragma unroll
        for (int m = 0; m < 4; m++) {
            int row = wrow * 64 + m * 16 + l15;
            int j0 = (l4 * 2) ^ (l15 & 7);
            const char* rp = bA + row * 128;
            f32x4 lo = *(const f32x4*)(rp + j0 * 16);
            f32x4 hi = *(const f32x4*)(rp + (j0 ^ 1) * 16);
            union { uint4 u; short8v s; } av;
            av.u = (uint4){cvtpk(lo.x, lo.y), cvtpk(lo.z, lo.w),
                           cvtpk(hi.x, hi.y), cvtpk(hi.z, hi.w)};
#pragma unroll
            for (int n = 0; n < 4; n++)
                acc[m][n] = __builtin_amdgcn_mfma_f32_16x16x32_bf16(av.s, bfr[n], acc[m][n], 0, 0, 0);
        }

        if (ks < 15) {
            asm volatile("s_waitcnt vmcnt(0)" ::: "memory");
            __builtin_amdgcn_s_barrier();
            __builtin_amdgcn_sched_barrier(0);
        }
    }
#undef QSTAGE

    __syncthreads();

    float qbv[4];
#pragma unroll
    for (int n = 0; n < 4; n++) qbv[n] = qb[wcol * 64 + n * 16 + l15];
#pragma unroll
    for (int m = 0; m < 4; m++) {
#pragma unroll
        for (int n = 0; n < 4; n++) {
#pragma unroll
            for (int r = 0; r < 4; r++) {
                int rl = m * 16 + l4 * 4 + r;
                int cl = n * 16 + l15;
                float x = acc[m][n][r] + qbv[n];
                float q = x > 0.f ? x + 1.f : __expf(x);
                int byte = wid * 8192 + ((rl * 128 + cl * 2) ^ ((rl & 7) << 4));
                *(ushort*)(smem + byte) = f2bf(q);
            }
        }
    }
    __syncthreads();

    const int bb = R0 >> 16;
#pragma unroll
    for (int hi = 0; hi < 2; hi++) {
        int h = wcol * 2 + hi;
        int bh = bb * 8 + h;
        const ushort* kb = kvt + (size_t)bh * 48 * 32;
        short8v bk0 = *(const short8v*)(kb + (0 * 16 + l15) * 32 + l4 * 8);
        short8v bk1 = *(const short8v*)(kb + (1 * 16 + l15) * 32 + l4 * 8);
        short8v bkz = *(const short8v*)(kb + (2 * 16 + l15) * 32 + l4 * 8);
#pragma unroll
        for (int m = 0; m < 4; m++) {
            int rl = m * 16 + l15;
            int byte = wid * 8192 + ((rl * 128 + hi * 64 + l4 * 16) ^ ((rl & 7) << 4));
            short8v aq = *(const short8v*)(smem + byte);
            f32x4 zero = (f32x4){0.f, 0.f, 0.f, 0.f};
            f32x4 o0 = __builtin_amdgcn_mfma_f32_16x16x32_bf16(aq, bk0, zero, 0, 0, 0);
            f32x4 o1 = __builtin_amdgcn_mfma_f32_16x16x32_bf16(aq, bk1, zero, 0, 0, 0);
            f32x4 oz = __builtin_amdgcn_mfma_f32_16x16x32_bf16(aq, bkz, zero, 0, 0, 0);
#pragma unroll
            for (int r = 0; r < 4; r++) {
                float z = __shfl(oz[r], (lane & 48));
                float sc = 1.f / (z + 1e-6f);
                int grow = R0 + wrow * 64 + m * 16 + l4 * 4 + r;
                int gcol = wcol * 64 + hi * 32 + l15;
                Out[(size_t)grow * 256 + gcol] = o0[r] * sc;
                Out[(size_t)grow * 256 + gcol + 16] = o1[r] * sc;
            }
        }
    }
}

extern "C" void kernel_launch(void* const* d_in, const int* in_sizes, int n_in,
                              void* d_out, int out_size, void* d_ws, size_t ws_size,
                              hipStream_t stream) {
    const float* query = (const float*)d_in[0];
    const float* key = (const float*)d_in[1];
    // d_in[2] = value: only its shape is used by the reference — never read.
    const float* mh = (const float*)d_in[3];
    const float* q_w = (const float*)d_in[4];
    const float* q_b = (const float*)d_in[5];
    const float* k_w = (const float*)d_in[6];
    const float* k_b = (const float*)d_in[7];
    const float* v_w = (const float*)d_in[8];
    const float* v_b = (const float*)d_in[9];
    const float* l1_w = (const float*)d_in[10];
    const float* l1_b = (const float*)d_in[11];
    const float* l2_w = (const float*)d_in[12];
    const float* l2_b = (const float*)d_in[13];
    const float* g1_w = (const float*)d_in[14];
    const float* g1_b = (const float*)d_in[15];
    const float* g2_w = (const float*)d_in[16];
    const float* g2_b = (const float*)d_in[17];

    float* out = (float*)d_out;
    float* ws = (float*)d_ws;

    float* ppart = ws + WS_PPART;
    float* glob = ws + WS_GLOB;
    float* kvp = ws + WS_KVP;
    float* ksp = ws + WS_KSP;
    ushort* kvt = (ushort*)(ws + WS_KVT);
    ushort* wfp = (ushort*)(ws + WS_WFP);
    ushort* l1t = (ushort*)(ws + WS_L1T);
    ushort* l2t = (ushort*)(ws + WS_L2T);
    ushort* kwt = (ushort*)(ws + WS_KWT);
    ushort* vwt = (ushort*)(ws + WS_VWT);

    // big intermediates inside d_out (qattn overwrites everything at the end)
    ushort* t = (ushort*)out;                      // 32768x256 bf16
    ushort* fre = (ushort*)(out + 4194304);        // 32768x256 bf16
    ushort* Km = (ushort*)(out + 8388608);         // 32768x256 bf16
    ushort* Vn = (ushort*)(out + 12582912);        // 32768x256 bf16

    k_prep<<<1792, 256, 0, stream>>>(l1_w, l2_w, k_w, v_w, mh, q_w, key,
                                     l1t, l2t, kwt, vwt, wfp, ppart);

    // t = relu(s @ l1_w + l1_b)  (blocks 0..511)  +  glob MLP (block 512), both dep only on prep
    gemm1_glob<<<513, 256, 0, stream>>>(key, l1t, l1_b, t,
                                        ppart, g1_w, g1_b, g2_w, g2_b, glob);

    // fre = sigmoid(t @ l2_w + l2_b + glob) * high + low
    gemm_bf<0, 1><<<512, 256, 0, stream>>>(t, l2t, l2_b, fre, glob, key);
    // Km = elu(fre@k_w+k_b)+1  and  Vn = fre@v_w+v_b  in ONE batched launch
    gemm_bf34<<<1024, 256, 0, stream>>>(fre, kwt, vwt, k_b, v_b, Km, Vn);

    k_kv_part<<<512, 256, 0, stream>>>(Km, Vn, kvp, ksp);
    k_kv_reduce<<<16, 256, 0, stream>>>(kvp, ksp, kvt);

    k_qattn_mfma<<<1024, 512, 0, stream>>>(query, wfp, q_b, kvt, out);
}

// Round 16
// 249.261 us; speedup vs baseline: 1.1008x; 1.0145x over previous
//
#include <hip/hip_runtime.h>
#include <math.h>

// Problem constants
#define BB 2

// ws layout (float offsets)
#define WS_PPART 0         // 2*128*256 pool partials
#define WS_GLOB  66048     // 2*256
#define WS_KVP   66560     // 16*32*1024 KV partials
#define WS_KSP   590848    // 16*32*32 Ksum partials
#define WS_KVT   607232    // bf16 KV_aug: 16*48*32 ushort
#define WS_WFP   619520    // bf16 Wf pre-tiled [16][256][32]: 131072 ushort
#define WS_L1T   685056    // bf16 l1 pre-tiled: 2*8*128*32 ushort
#define WS_L2T   717824
#define WS_KWT   750592
#define WS_VWT   783360

typedef __attribute__((ext_vector_type(8))) short short8v;
typedef __attribute__((ext_vector_type(4))) float f32x4;

__device__ __forceinline__ ushort f2bf(float x) {
    union { float f; unsigned int u; } v; v.f = x;
    unsigned int u = v.u;
    unsigned int r = (u + 0x7fffu + ((u >> 16) & 1u)) >> 16;
    return (ushort)r;
}

__device__ __forceinline__ float bf2f(ushort x) {
    union { float f; unsigned int u; } v;
    v.u = ((unsigned int)x) << 16;
    return v.f;
}

// packed f32x2 -> bf16x2 (RNE), 1 VALU op
__device__ __forceinline__ unsigned int cvtpk(float lo, float hi) {
    unsigned int d;
    asm("v_cvt_pk_bf16_f32 %0, %1, %2" : "=v"(d) : "v"(lo), "v"(hi));
    return d;
}

// async global->LDS, 16B per lane; LDS dest is wave-uniform base (+lane*16 by HW)
__device__ __forceinline__ void gload16(const void* g, void* l) {
    __builtin_amdgcn_global_load_lds(
        (const __attribute__((address_space(1))) unsigned int*)g,
        (__attribute__((address_space(3))) unsigned int*)l, 16, 0, 0);
}

// ---------------- merged prep: weight tiling + Wf fuse + pool partials ----------------
// SINGLE CHANGE vs R15: pool gather uses 4 independent accumulators (breaks the
// 128-long serial load->add chain; 4x memory-level parallelism on the latency-bound phase).
__global__ __launch_bounds__(256) void k_prep(const float* __restrict__ l1w, const float* __restrict__ l2w,
                                              const float* __restrict__ kw, const float* __restrict__ vw,
                                              const float* __restrict__ mh, const float* __restrict__ qw,
                                              const float* __restrict__ key,
                                              ushort* __restrict__ t0, ushort* __restrict__ t1,
                                              ushort* __restrict__ t2, ushort* __restrict__ t3,
                                              ushort* __restrict__ wfp, float* __restrict__ ppart) {
    int blk = blockIdx.x, t = threadIdx.x;
    if (blk < 1024) {
        int mat = blk >> 8, k = blk & 255, n = t;
        const float* w = mat == 0 ? l1w : mat == 1 ? l2w : mat == 2 ? kw : vw;
        ushort* o = mat == 0 ? t0 : mat == 1 ? t1 : mat == 2 ? t2 : t3;
        o[(((size_t)(n >> 7) * 8 + (k >> 5)) * 128 + (n & 127)) * 32 + (k & 31)] = f2bf(w[k * 256 + n]);
    } else if (blk < 1536) {
        __shared__ float mr[256];
        int g = blk - 1024;
        mr[t] = mh[g * 256 + t];
        __syncthreads();
        float acc = 0.f;
        for (int k = 0; k < 256; k++) acc += mr[k] * qw[k * 256 + t];
        wfp[(((size_t)(g >> 5) * 256 + t) * 32 + (g & 31))] = f2bf(acc);
    } else {
        int p = blk - 1536;
        int b = p >> 7, ci = p & 127;
        float a0 = 0.f, a1 = 0.f, a2 = 0.f, a3 = 0.f;
        size_t base = ((size_t)b * 65536 + (size_t)(2 * ci + 1) * 256 + 1) * 256 + t;
        for (int q = 0; q < 128; q += 4) {
            a0 += key[base + (size_t)(2 * q + 0) * 256];
            a1 += key[base + (size_t)(2 * q + 2) * 256];
            a2 += key[base + (size_t)(2 * q + 4) * 256];
            a3 += key[base + (size_t)(2 * q + 6) * 256];
        }
        ppart[(size_t)p * 256 + t] = (a0 + a1) + (a2 + a3);
    }
}

// ---------------- gemm1 (t = relu(s@l1+b), blocks 0..511) + glob2 body (block 512) (R15-exact) ----------------
__global__ __launch_bounds__(256) void gemm1_glob(const float* __restrict__ key,
                                                  const ushort* __restrict__ Wt,
                                                  const float* __restrict__ bias,
                                                  ushort* __restrict__ Outp,
                                                  const float* __restrict__ ppart,
                                                  const float* __restrict__ g1w,
                                                  const float* __restrict__ g1b,
                                                  const float* __restrict__ g2w,
                                                  const float* __restrict__ g2b,
                                                  float* __restrict__ glob) {
    __shared__ __align__(16) ushort smem[8192];   // gemm: As 8KB | Bs 8KB; glob block reuses as pl/hid

    const int tid = threadIdx.x;

    if (blockIdx.x == 512) {
        float* pl = (float*)smem;          // 256 floats
        float* hid = (float*)smem + 256;   // 256 floats
        for (int b = 0; b < BB; b++) {
            float s = 0.f;
            for (int p = 0; p < 128; p++) s += ppart[((size_t)b * 128 + p) * 256 + tid];
            pl[tid] = s * (2.f / 16384.f);
            __syncthreads();
            float acc = g1b[tid];
            for (int k = 0; k < 256; k++) acc += pl[k] * g1w[k * 256 + tid];
            hid[tid] = fmaxf(acc, 0.f);
            __syncthreads();
            float a2 = g2b[tid];
            for (int k = 0; k < 256; k++) a2 += hid[k] * g2w[k * 256 + tid];
            glob[b * 256 + tid] = a2;
            __syncthreads();
        }
        return;
    }

    ushort* As = smem;
    ushort* Bs = smem + 4096;

    const int lane = tid & 63;
    const int w = tid >> 6;
    const int wrow = w >> 1, wcol = w & 1;
    const int bx = blockIdx.x & 1;
    const int by = blockIdx.x >> 1;
    const int r0 = by * 128, n0 = bx * 128;
    const int l15 = lane & 15, l4 = lane >> 4;

    const int loff = lane * 16;
    char* ldsB0 = (char*)Bs + w * 2048;
    char* ldsB1 = (char*)Bs + w * 2048 + 1024;
    const int srow = tid >> 1, shalf = tid & 1;
    size_t agbase;
    {
        int r = r0 + srow;
        int b = r >> 14, rr = r & 16383;
        int ii = rr >> 7, jj = rr & 127;
        agbase = ((size_t)b * 65536 + (size_t)(2 * ii + 1) * 256 + (2 * jj + 1)) * 256 + shalf * 16;
    }

    f32x4 acc[4][4];
#pragma unroll
    for (int i = 0; i < 4; i++)
#pragma unroll
        for (int j = 0; j < 4; j++) acc[i][j] = (f32x4){0.f, 0.f, 0.f, 0.f};

    for (int ks = 0; ks < 8; ks++) {
        const char* btile = (const char*)Wt + (size_t)(bx * 8 + ks) * 8192;
        gload16(btile + w * 2048 + loff, ldsB0);
        gload16(btile + w * 2048 + 1024 + loff, ldsB1);
        {
            float4 f0 = *(const float4*)(key + agbase + (size_t)ks * 32);
            float4 f1 = *(const float4*)(key + agbase + (size_t)ks * 32 + 4);
            float4 f2 = *(const float4*)(key + agbase + (size_t)ks * 32 + 8);
            float4 f3 = *(const float4*)(key + agbase + (size_t)ks * 32 + 12);
            uint4 lo = {cvtpk(f0.x * 2.f, f0.y * 2.f), cvtpk(f0.z * 2.f, f0.w * 2.f),
                        cvtpk(f1.x * 2.f, f1.y * 2.f), cvtpk(f1.z * 2.f, f1.w * 2.f)};
            uint4 hi = {cvtpk(f2.x * 2.f, f2.y * 2.f), cvtpk(f2.z * 2.f, f2.w * 2.f),
                        cvtpk(f3.x * 2.f, f3.y * 2.f), cvtpk(f3.z * 2.f, f3.w * 2.f)};
            *(uint4*)((char*)As + srow * 64 + shalf * 32) = lo;
            *(uint4*)((char*)As + srow * 64 + shalf * 32 + 16) = hi;
        }
        __syncthreads();

        short8v a[4], bfr[4];
#pragma unroll
        for (int m = 0; m < 4; m++)
            a[m] = *(const short8v*)((const char*)As + (wrow * 64 + m * 16 + l15) * 64 + l4 * 16);
#pragma unroll
        for (int n = 0; n < 4; n++)
            bfr[n] = *(const short8v*)((const char*)Bs + (wcol * 64 + n * 16 + l15) * 64 + l4 * 16);
#pragma unroll
        for (int m = 0; m < 4; m++)
#pragma unroll
            for (int n = 0; n < 4; n++)
                acc[m][n] = __builtin_amdgcn_mfma_f32_16x16x32_bf16(a[m], bfr[n], acc[m][n], 0, 0, 0);
        __syncthreads();
    }

    float bv[4];
#pragma unroll
    for (int n = 0; n < 4; n++) bv[n] = bias[n0 + wcol * 64 + n * 16 + l15];
#pragma unroll
    for (int m = 0; m < 4; m++) {
#pragma unroll
        for (int n = 0; n < 4; n++) {
            int c = n0 + wcol * 64 + n * 16 + l15;
#pragma unroll
            for (int r = 0; r < 4; r++) {
                int R = r0 + wrow * 64 + m * 16 + l4 * 4 + r;
                float x = acc[m][n][r] + bv[n];
                Outp[(size_t)R * 256 + c] = f2bf(fmaxf(x, 0.f));
            }
        }
    }
}

// ---------------- bf16 MFMA mid GEMM (R15-exact, used for gemm2 only) ----------------
template <int AMODE, int EPI>
__global__ __launch_bounds__(256) void gemm_bf(const void* __restrict__ Asrc_,
                                               const ushort* __restrict__ Wt,
                                               const float* __restrict__ bias,
                                               void* __restrict__ Outp,
                                               const float* __restrict__ glob,
                                               const float* __restrict__ key) {
    __shared__ __align__(16) ushort smem[8192];   // As 8KB | Bs 8KB
    ushort* As = smem;
    ushort* Bs = smem + 4096;

    const int tid = threadIdx.x;
    const int lane = tid & 63;
    const int w = tid >> 6;
    const int wrow = w >> 1, wcol = w & 1;
    const int bx = blockIdx.x & 1;
    const int by = blockIdx.x >> 1;
    const int r0 = by * 128, n0 = bx * 128;
    const int l15 = lane & 15, l4 = lane >> 4;

    const int loff = lane * 16;
    char* ldsB0 = (char*)Bs + w * 2048;
    char* ldsB1 = (char*)Bs + w * 2048 + 1024;
    const int rowA0 = w * 32 + (lane >> 2);
    const int kbA = (lane & 3) * 16;
    char* ldsA0 = (char*)As + w * 2048;
    char* ldsA1 = (char*)As + w * 2048 + 1024;
    const int srow = tid >> 1, shalf = tid & 1;
    size_t agbase = 0;
    if constexpr (AMODE == 1) {
        int r = r0 + srow;
        int b = r >> 14, rr = r & 16383;
        int ii = rr >> 7, jj = rr & 127;
        agbase = ((size_t)b * 65536 + (size_t)(2 * ii + 1) * 256 + (2 * jj + 1)) * 256 + shalf * 16;
    }

    f32x4 acc[4][4];
#pragma unroll
    for (int i = 0; i < 4; i++)
#pragma unroll
        for (int j = 0; j < 4; j++) acc[i][j] = (f32x4){0.f, 0.f, 0.f, 0.f};

    for (int ks = 0; ks < 8; ks++) {
        const char* btile = (const char*)Wt + (size_t)(bx * 8 + ks) * 8192;
        gload16(btile + w * 2048 + loff, ldsB0);
        gload16(btile + w * 2048 + 1024 + loff, ldsB1);
        if constexpr (AMODE == 0) {
            const char* ab = (const char*)Asrc_;
            gload16(ab + (size_t)(r0 + rowA0) * 512 + ks * 64 + kbA, ldsA0);
            gload16(ab + (size_t)(r0 + rowA0 + 16) * 512 + ks * 64 + kbA, ldsA1);
        } else {
            const float* kf = (const float*)Asrc_;
            float4 f0 = *(const float4*)(kf + agbase + (size_t)ks * 32);
            float4 f1 = *(const float4*)(kf + agbase + (size_t)ks * 32 + 4);
            float4 f2 = *(const float4*)(kf + agbase + (size_t)ks * 32 + 8);
            float4 f3 = *(const float4*)(kf + agbase + (size_t)ks * 32 + 12);
            uint4 lo = {cvtpk(f0.x * 2.f, f0.y * 2.f), cvtpk(f0.z * 2.f, f0.w * 2.f),
                        cvtpk(f1.x * 2.f, f1.y * 2.f), cvtpk(f1.z * 2.f, f1.w * 2.f)};
            uint4 hi = {cvtpk(f2.x * 2.f, f2.y * 2.f), cvtpk(f2.z * 2.f, f2.w * 2.f),
                        cvtpk(f3.x * 2.f, f3.y * 2.f), cvtpk(f3.z * 2.f, f3.w * 2.f)};
            *(uint4*)((char*)As + srow * 64 + shalf * 32) = lo;
            *(uint4*)((char*)As + srow * 64 + shalf * 32 + 16) = hi;
        }
        __syncthreads();

        short8v a[4], bfr[4];
#pragma unroll
        for (int m = 0; m < 4; m++)
            a[m] = *(const short8v*)((const char*)As + (wrow * 64 + m * 16 + l15) * 64 + l4 * 16);
#pragma unroll
        for (int n = 0; n < 4; n++)
            bfr[n] = *(const short8v*)((const char*)Bs + (wcol * 64 + n * 16 + l15) * 64 + l4 * 16);
#pragma unroll
        for (int m = 0; m < 4; m++)
#pragma unroll
            for (int n = 0; n < 4; n++)
                acc[m][n] = __builtin_amdgcn_mfma_f32_16x16x32_bf16(a[m], bfr[n], acc[m][n], 0, 0, 0);
        __syncthreads();
    }

    const int b = r0 >> 14;
    float bv[4], gv[4];
#pragma unroll
    for (int n = 0; n < 4; n++) {
        int c = n0 + wcol * 64 + n * 16 + l15;
        bv[n] = bias[c];
        if constexpr (EPI == 1) gv[n] = glob[b * 256 + c];
    }
#pragma unroll
    for (int m = 0; m < 4; m++) {
#pragma unroll
        for (int n = 0; n < 4; n++) {
            int c = n0 + wcol * 64 + n * 16 + l15;
#pragma unroll
            for (int r = 0; r < 4; r++) {
                int row = wrow * 64 + m * 16 + l4 * 4 + r;
                int R = r0 + row;
                float x = acc[m][n][r] + bv[n];
                if constexpr (EPI == 0) {
                    ((ushort*)Outp)[(size_t)R * 256 + c] = f2bf(fmaxf(x, 0.f));
                } else {
                    int rr = R & 16383;
                    int ii = rr >> 7, jj = rr & 127;
                    size_t kb = ((size_t)b * 65536 + (size_t)(2 * ii) * 256 + 2 * jj) * 256 + c;
                    float ka = key[kb];
                    float kb2 = key[kb + 256];
                    float kc2 = key[kb + 65536];
                    float kd2 = key[kb + 65536 + 256];
                    float low = 0.5f * (ka + kb2 + kc2 + kd2);
                    float high = 0.5f * (3.f * kd2 - ka - kb2 - kc2);
                    float wei = 1.f / (1.f + __expf(-(x + gv[n])));
                    ((ushort*)Outp)[(size_t)R * 256 + c] = f2bf(wei * high + low);
                }
            }
        }
    }
}

// ---------------- batched K/V GEMM (R15-exact) ----------------
__global__ __launch_bounds__(256) void gemm_bf34(const ushort* __restrict__ Afre,
                                                 const ushort* __restrict__ kwt,
                                                 const ushort* __restrict__ vwt,
                                                 const float* __restrict__ kbias,
                                                 const float* __restrict__ vbias,
                                                 ushort* __restrict__ Km,
                                                 ushort* __restrict__ Vn) {
    __shared__ __align__(16) ushort smem[8192];   // As 8KB | Bs 8KB
    ushort* As = smem;
    ushort* Bs = smem + 4096;

    const int isV = blockIdx.x >= 512;
    const int blk = blockIdx.x & 511;
    const ushort* Wt = isV ? vwt : kwt;
    const float* bias = isV ? vbias : kbias;
    ushort* Outp = isV ? Vn : Km;

    const int tid = threadIdx.x;
    const int lane = tid & 63;
    const int w = tid >> 6;
    const int wrow = w >> 1, wcol = w & 1;
    const int bx = blk & 1;
    const int by = blk >> 1;
    const int r0 = by * 128, n0 = bx * 128;
    const int l15 = lane & 15, l4 = lane >> 4;

    const int loff = lane * 16;
    char* ldsB0 = (char*)Bs + w * 2048;
    char* ldsB1 = (char*)Bs + w * 2048 + 1024;
    const int rowA0 = w * 32 + (lane >> 2);
    const int kbA = (lane & 3) * 16;
    char* ldsA0 = (char*)As + w * 2048;
    char* ldsA1 = (char*)As + w * 2048 + 1024;

    f32x4 acc[4][4];
#pragma unroll
    for (int i = 0; i < 4; i++)
#pragma unroll
        for (int j = 0; j < 4; j++) acc[i][j] = (f32x4){0.f, 0.f, 0.f, 0.f};

    for (int ks = 0; ks < 8; ks++) {
        const char* btile = (const char*)Wt + (size_t)(bx * 8 + ks) * 8192;
        gload16(btile + w * 2048 + loff, ldsB0);
        gload16(btile + w * 2048 + 1024 + loff, ldsB1);
        const char* ab = (const char*)Afre;
        gload16(ab + (size_t)(r0 + rowA0) * 512 + ks * 64 + kbA, ldsA0);
        gload16(ab + (size_t)(r0 + rowA0 + 16) * 512 + ks * 64 + kbA, ldsA1);
        __syncthreads();

        short8v a[4], bfr[4];
#pragma unroll
        for (int m = 0; m < 4; m++)
            a[m] = *(const short8v*)((const char*)As + (wrow * 64 + m * 16 + l15) * 64 + l4 * 16);
#pragma unroll
        for (int n = 0; n < 4; n++)
            bfr[n] = *(const short8v*)((const char*)Bs + (wcol * 64 + n * 16 + l15) * 64 + l4 * 16);
#pragma unroll
        for (int m = 0; m < 4; m++)
#pragma unroll
            for (int n = 0; n < 4; n++)
                acc[m][n] = __builtin_amdgcn_mfma_f32_16x16x32_bf16(a[m], bfr[n], acc[m][n], 0, 0, 0);
        __syncthreads();
    }

    float bv[4];
#pragma unroll
    for (int n = 0; n < 4; n++) bv[n] = bias[n0 + wcol * 64 + n * 16 + l15];
#pragma unroll
    for (int m = 0; m < 4; m++) {
#pragma unroll
        for (int n = 0; n < 4; n++) {
            int c = n0 + wcol * 64 + n * 16 + l15;
#pragma unroll
            for (int r = 0; r < 4; r++) {
                int R = r0 + wrow * 64 + m * 16 + l4 * 4 + r;
                float x = acc[m][n][r] + bv[n];
                float o = isV ? x : ((x > 0.f) ? x + 1.f : __expf(x));
                Outp[(size_t)R * 256 + c] = f2bf(o);
            }
        }
    }
}

// ---------------- KV partials (bf16 in, R7-exact 8-row stages) ----------------
__global__ __launch_bounds__(256) void k_kv_part(const ushort* __restrict__ Km,
                                                 const ushort* __restrict__ Vn,
                                                 float* __restrict__ kvp,
                                                 float* __restrict__ ksp) {
    __shared__ float Kl[8][33];
    __shared__ float Vl[8][33];
    int t = threadIdx.x;
    int c = blockIdx.x & 31, h = (blockIdx.x >> 5) & 7, b = blockIdx.x >> 8;
    int d = t >> 3, vq = (t & 7) * 4;
    int lr = t >> 5, lc = t & 31;
    float acc0 = 0, acc1 = 0, acc2 = 0, acc3 = 0, ks = 0;
    size_t rowbase = (size_t)b * 16384 + (size_t)c * 512;
    for (int s0 = 0; s0 < 512; s0 += 8) {
        size_t idx = (rowbase + s0 + lr) * 256 + h * 32 + lc;
        Kl[lr][lc] = bf2f(Km[idx]);
        Vl[lr][lc] = bf2f(Vn[idx]);
        __syncthreads();
#pragma unroll
        for (int rr = 0; rr < 8; rr++) {
            float kd = Kl[rr][d];
            acc0 += kd * Vl[rr][vq];
            acc1 += kd * Vl[rr][vq + 1];
            acc2 += kd * Vl[rr][vq + 2];
            acc3 += kd * Vl[rr][vq + 3];
            ks += kd;
        }
        __syncthreads();
    }
    size_t ob = ((size_t)(b * 8 + h) * 32 + c) * 1024 + d * 32 + vq;
    kvp[ob] = acc0; kvp[ob + 1] = acc1; kvp[ob + 2] = acc2; kvp[ob + 3] = acc3;
    if ((t & 7) == 0) ksp[((b * 8 + h) * 32 + c) * 32 + d] = ks;
}

// ---------------- KV reduce -> bf16 augmented B^T: KVt[bh][48][32] (R7-exact) ----------------
__global__ __launch_bounds__(256) void k_kv_reduce(const float* __restrict__ kvp,
                                                   const float* __restrict__ ksp,
                                                   ushort* __restrict__ kvt) {
    int bh = blockIdx.x, t = threadIdx.x;
    for (int e = t; e < 1024; e += 256) {
        float s = 0.f;
        for (int cc = 0; cc < 32; cc++) s += kvp[((size_t)bh * 32 + cc) * 1024 + e];
        int d = e >> 5, v = e & 31;
        kvt[((size_t)bh * 48 + v) * 32 + d] = f2bf(s);
    }
    if (t < 32) {
        float s = 0.f;
        for (int cc = 0; cc < 32; cc++) s += ksp[(bh * 32 + cc) * 32 + t];
        kvt[((size_t)bh * 48 + 32) * 32 + t] = f2bf(s);
    }
    for (int z = t; z < 480; z += 256) kvt[(size_t)bh * 48 * 32 + 33 * 32 + z] = 0;
}

// ---------------- MFMA q-GEMM (BM=128, BN=256, BK=32), 2-phase pipelined (R7 BEST, byte-exact) ----------------
__global__ __launch_bounds__(512, 4) void k_qattn_mfma(const float* __restrict__ query,
                                                       const ushort* __restrict__ wfp,
                                                       const float* __restrict__ qb,
                                                       const ushort* __restrict__ kvt,
                                                       float* __restrict__ Out) {
    __shared__ __align__(16) char smem[65536];
    char* As0 = smem;                // [128][32] f32 (16KB)
    char* As1 = smem + 16384;
    char* Bs0 = smem + 32768;        // [256][32] bf16 (16KB)
    char* Bs1 = smem + 49152;

    const int tid = threadIdx.x;
    const int lane = tid & 63;
    const int wid = tid >> 6;            // 0..7
    const int wrow = wid >> 2, wcol = wid & 3;
    const int R0 = blockIdx.x * 128;
    const int l15 = lane & 15, l4 = lane >> 4;

    const int arow0 = wid * 16 + (lane >> 3);
    const int achunk = (lane & 7) ^ (lane >> 3);
    const float* aga = query + (size_t)(R0 + arow0) * 512 + achunk * 4;
    const int wb = wid * 2048;
    const int bglo = wb + lane * 16;

    f32x4 acc[4][4];
#pragma unroll
    for (int i = 0; i < 4; i++)
#pragma unroll
        for (int j = 0; j < 4; j++) acc[i][j] = (f32x4){0.f, 0.f, 0.f, 0.f};

#define QSTAGE(dA, dB, kss)                                                     \
    do {                                                                        \
        const float* ga_ = aga + (size_t)(kss) * 32;                            \
        gload16(ga_, (dA) + wb);                                                \
        gload16(ga_ + 8 * 512, (dA) + wb + 1024);                               \
        const char* pan_ = (const char*)wfp + (size_t)(kss) * 16384 + bglo;     \
        gload16(pan_, (dB) + wb);                                               \
        gload16(pan_ + 1024, (dB) + wb + 1024);                                 \
    } while (0)

    QSTAGE(As0, Bs0, 0);
    asm volatile("s_waitcnt vmcnt(0)" ::: "memory");
    __builtin_amdgcn_s_barrier();
    __builtin_amdgcn_sched_barrier(0);

    for (int ks = 0; ks < 16; ks++) {
        const char* bA = (ks & 1) ? As1 : As0;
        const char* bB = (ks & 1) ? Bs1 : Bs0;
        char* nA = (ks & 1) ? As0 : As1;
        char* nB = (ks & 1) ? Bs0 : Bs1;
        if (ks < 15) QSTAGE(nA, nB, ks + 1);

        short8v bfr[4];
#pragma unroll
        for (int n = 0; n < 4; n++)
            bfr[n] = *(const short8v*)(bB + (wcol * 64 + n * 16 + l15) * 64 + l4 * 16);
#pragma unroll
        for (int m = 0; m < 4; m++) {
            int row = wrow * 64 + m * 16 + l15;
            int j0 = (l4 * 2) ^ (l15 & 7);
            const char* rp = bA + row * 128;
            f32x4 lo = *(const f32x4*)(rp + j0 * 16);
            f32x4 hi = *(const f32x4*)(rp + (j0 ^ 1) * 16);
            union { uint4 u; short8v s; } av;
            av.u = (uint4){cvtpk(lo.x, lo.y), cvtpk(lo.z, lo.w),
                           cvtpk(hi.x, hi.y), cvtpk(hi.z, hi.w)};
#pragma unroll
            for (int n = 0; n < 4; n++)
                acc[m][n] = __builtin_amdgcn_mfma_f32_16x16x32_bf16(av.s, bfr[n], acc[m][n], 0, 0, 0);
        }

        if (ks < 15) {
            asm volatile("s_waitcnt vmcnt(0)" ::: "memory");
            __builtin_amdgcn_s_barrier();
            __builtin_amdgcn_sched_barrier(0);
        }
    }
#undef QSTAGE

    __syncthreads();

    float qbv[4];
#pragma unroll
    for (int n = 0; n < 4; n++) qbv[n] = qb[wcol * 64 + n * 16 + l15];
#pragma unroll
    for (int m = 0; m < 4; m++) {
#pragma unroll
        for (int n = 0; n < 4; n++) {
#pragma unroll
            for (int r = 0; r < 4; r++) {
                int rl = m * 16 + l4 * 4 + r;
                int cl = n * 16 + l15;
                float x = acc[m][n][r] + qbv[n];
                float q = x > 0.f ? x + 1.f : __expf(x);
                int byte = wid * 8192 + ((rl * 128 + cl * 2) ^ ((rl & 7) << 4));
                *(ushort*)(smem + byte) = f2bf(q);
            }
        }
    }
    __syncthreads();

    const int bb = R0 >> 16;
#pragma unroll
    for (int hi = 0; hi < 2; hi++) {
        int h = wcol * 2 + hi;
        int bh = bb * 8 + h;
        const ushort* kb = kvt + (size_t)bh * 48 * 32;
        short8v bk0 = *(const short8v*)(kb + (0 * 16 + l15) * 32 + l4 * 8);
        short8v bk1 = *(const short8v*)(kb + (1 * 16 + l15) * 32 + l4 * 8);
        short8v bkz = *(const short8v*)(kb + (2 * 16 + l15) * 32 + l4 * 8);
#pragma unroll
        for (int m = 0; m < 4; m++) {
            int rl = m * 16 + l15;
            int byte = wid * 8192 + ((rl * 128 + hi * 64 + l4 * 16) ^ ((rl & 7) << 4));
            short8v aq = *(const short8v*)(smem + byte);
            f32x4 zero = (f32x4){0.f, 0.f, 0.f, 0.f};
            f32x4 o0 = __builtin_amdgcn_mfma_f32_16x16x32_bf16(aq, bk0, zero, 0, 0, 0);
            f32x4 o1 = __builtin_amdgcn_mfma_f32_16x16x32_bf16(aq, bk1, zero, 0, 0, 0);
            f32x4 oz = __builtin_amdgcn_mfma_f32_16x16x32_bf16(aq, bkz, zero, 0, 0, 0);
#pragma unroll
            for (int r = 0; r < 4; r++) {
                float z = __shfl(oz[r], (lane & 48));
                float sc = 1.f / (z + 1e-6f);
                int grow = R0 + wrow * 64 + m * 16 + l4 * 4 + r;
                int gcol = wcol * 64 + hi * 32 + l15;
                Out[(size_t)grow * 256 + gcol] = o0[r] * sc;
                Out[(size_t)grow * 256 + gcol + 16] = o1[r] * sc;
            }
        }
    }
}

extern "C" void kernel_launch(void* const* d_in, const int* in_sizes, int n_in,
                              void* d_out, int out_size, void* d_ws, size_t ws_size,
                              hipStream_t stream) {
    const float* query = (const float*)d_in[0];
    const float* key = (const float*)d_in[1];
    // d_in[2] = value: only its shape is used by the reference — never read.
    const float* mh = (const float*)d_in[3];
    const float* q_w = (const float*)d_in[4];
    const float* q_b = (const float*)d_in[5];
    const float* k_w = (const float*)d_in[6];
    const float* k_b = (const float*)d_in[7];
    const float* v_w = (const float*)d_in[8];
    const float* v_b = (const float*)d_in[9];
    const float* l1_w = (const float*)d_in[10];
    const float* l1_b = (const float*)d_in[11];
    const float* l2_w = (const float*)d_in[12];
    const float* l2_b = (const float*)d_in[13];
    const float* g1_w = (const float*)d_in[14];
    const float* g1_b = (const float*)d_in[15];
    const float* g2_w = (const float*)d_in[16];
    const float* g2_b = (const float*)d_in[17];

    float* out = (float*)d_out;
    float* ws = (float*)d_ws;

    float* ppart = ws + WS_PPART;
    float* glob = ws + WS_GLOB;
    float* kvp = ws + WS_KVP;
    float* ksp = ws + WS_KSP;
    ushort* kvt = (ushort*)(ws + WS_KVT);
    ushort* wfp = (ushort*)(ws + WS_WFP);
    ushort* l1t = (ushort*)(ws + WS_L1T);
    ushort* l2t = (ushort*)(ws + WS_L2T);
    ushort* kwt = (ushort*)(ws + WS_KWT);
    ushort* vwt = (ushort*)(ws + WS_VWT);

    // big intermediates inside d_out (qattn overwrites everything at the end)
    ushort* t = (ushort*)out;                      // 32768x256 bf16
    ushort* fre = (ushort*)(out + 4194304);        // 32768x256 bf16
    ushort* Km = (ushort*)(out + 8388608);         // 32768x256 bf16
    ushort* Vn = (ushort*)(out + 12582912);        // 32768x256 bf16

    k_prep<<<1792, 256, 0, stream>>>(l1_w, l2_w, k_w, v_w, mh, q_w, key,
                                     l1t, l2t, kwt, vwt, wfp, ppart);

    // t = relu(s @ l1_w + l1_b)  (blocks 0..511)  +  glob MLP (block 512), both dep only on prep
    gemm1_glob<<<513, 256, 0, stream>>>(key, l1t, l1_b, t,
                                        ppart, g1_w, g1_b, g2_w, g2_b, glob);

    // fre = sigmoid(t @ l2_w + l2_b + glob) * high + low
    gemm_bf<0, 1><<<512, 256, 0, stream>>>(t, l2t, l2_b, fre, glob, key);
    // Km = elu(fre@k_w+k_b)+1  and  Vn = fre@v_w+v_b  in ONE batched launch
    gemm_bf34<<<1024, 256, 0, stream>>>(fre, kwt, vwt, k_b, v_b, Km, Vn);

    k_kv_part<<<512, 256, 0, stream>>>(Km, Vn, kvp, ksp);
    k_kv_reduce<<<16, 256, 0, stream>>>(kvp, ksp, kvt);

    k_qattn_mfma<<<1024, 512, 0, stream>>>(query, wfp, q_b, kvt, out);
}

// Round 17
// 246.350 us; speedup vs baseline: 1.1138x; 1.0118x over previous
//
#include <hip/hip_runtime.h>
#include <math.h>

// Problem constants
#define BB 2

// ws layout (float offsets)
#define WS_PPART 0         // 2*128*256 pool partials
#define WS_GLOB  66048     // 2*256
#define WS_KVP   66560     // 16*32*1024 KV partials
#define WS_KSP   590848    // 16*32*32 Ksum partials
#define WS_KVT   607232    // bf16 KV_aug: 16*48*32 ushort
#define WS_WFP   619520    // bf16 Wf pre-tiled [16][256][32]: 131072 ushort
#define WS_L1T   685056    // bf16 l1 pre-tiled: 2*8*128*32 ushort
#define WS_L2T   717824
#define WS_KWT   750592
#define WS_VWT   783360

typedef __attribute__((ext_vector_type(8))) short short8v;
typedef __attribute__((ext_vector_type(4))) float f32x4;

__device__ __forceinline__ ushort f2bf(float x) {
    union { float f; unsigned int u; } v; v.f = x;
    unsigned int u = v.u;
    unsigned int r = (u + 0x7fffu + ((u >> 16) & 1u)) >> 16;
    return (ushort)r;
}

__device__ __forceinline__ float bf2f(ushort x) {
    union { float f; unsigned int u; } v;
    v.u = ((unsigned int)x) << 16;
    return v.f;
}

// packed f32x2 -> bf16x2 (RNE), 1 VALU op
__device__ __forceinline__ unsigned int cvtpk(float lo, float hi) {
    unsigned int d;
    asm("v_cvt_pk_bf16_f32 %0, %1, %2" : "=v"(d) : "v"(lo), "v"(hi));
    return d;
}

// async global->LDS, 16B per lane; LDS dest is wave-uniform base (+lane*16 by HW)
__device__ __forceinline__ void gload16(const void* g, void* l) {
    __builtin_amdgcn_global_load_lds(
        (const __attribute__((address_space(1))) unsigned int*)g,
        (__attribute__((address_space(3))) unsigned int*)l, 16, 0, 0);
}

// ---------------- merged prep: weight tiling + Wf fuse + pool partials (R16-exact) ----------------
__global__ __launch_bounds__(256) void k_prep(const float* __restrict__ l1w, const float* __restrict__ l2w,
                                              const float* __restrict__ kw, const float* __restrict__ vw,
                                              const float* __restrict__ mh, const float* __restrict__ qw,
                                              const float* __restrict__ key,
                                              ushort* __restrict__ t0, ushort* __restrict__ t1,
                                              ushort* __restrict__ t2, ushort* __restrict__ t3,
                                              ushort* __restrict__ wfp, float* __restrict__ ppart) {
    int blk = blockIdx.x, t = threadIdx.x;
    if (blk < 1024) {
        int mat = blk >> 8, k = blk & 255, n = t;
        const float* w = mat == 0 ? l1w : mat == 1 ? l2w : mat == 2 ? kw : vw;
        ushort* o = mat == 0 ? t0 : mat == 1 ? t1 : mat == 2 ? t2 : t3;
        o[(((size_t)(n >> 7) * 8 + (k >> 5)) * 128 + (n & 127)) * 32 + (k & 31)] = f2bf(w[k * 256 + n]);
    } else if (blk < 1536) {
        __shared__ float mr[256];
        int g = blk - 1024;
        mr[t] = mh[g * 256 + t];
        __syncthreads();
        float acc = 0.f;
        for (int k = 0; k < 256; k++) acc += mr[k] * qw[k * 256 + t];
        wfp[(((size_t)(g >> 5) * 256 + t) * 32 + (g & 31))] = f2bf(acc);
    } else {
        int p = blk - 1536;
        int b = p >> 7, ci = p & 127;
        float a0 = 0.f, a1 = 0.f, a2 = 0.f, a3 = 0.f;
        size_t base = ((size_t)b * 65536 + (size_t)(2 * ci + 1) * 256 + 1) * 256 + t;
        for (int q = 0; q < 128; q += 4) {
            a0 += key[base + (size_t)(2 * q + 0) * 256];
            a1 += key[base + (size_t)(2 * q + 2) * 256];
            a2 += key[base + (size_t)(2 * q + 4) * 256];
            a3 += key[base + (size_t)(2 * q + 6) * 256];
        }
        ppart[(size_t)p * 256 + t] = (a0 + a1) + (a2 + a3);
    }
}

// ---------------- gemm1 (blocks 0..511) + glob2 body (block 512) ----------------
// SINGLE CHANGE vs R16: glob body uses 4 independent accumulators in its three
// reduction loops (it is the critical path of this launch; same latency-chain
// mechanism that won in R16's prep pool-gather).
__global__ __launch_bounds__(256) void gemm1_glob(const float* __restrict__ key,
                                                  const ushort* __restrict__ Wt,
                                                  const float* __restrict__ bias,
                                                  ushort* __restrict__ Outp,
                                                  const float* __restrict__ ppart,
                                                  const float* __restrict__ g1w,
                                                  const float* __restrict__ g1b,
                                                  const float* __restrict__ g2w,
                                                  const float* __restrict__ g2b,
                                                  float* __restrict__ glob) {
    __shared__ __align__(16) ushort smem[8192];   // gemm: As 8KB | Bs 8KB; glob block reuses as pl/hid

    const int tid = threadIdx.x;

    if (blockIdx.x == 512) {
        float* pl = (float*)smem;          // 256 floats
        float* hid = (float*)smem + 256;   // 256 floats
        for (int b = 0; b < BB; b++) {
            float s0 = 0.f, s1 = 0.f, s2 = 0.f, s3 = 0.f;
            for (int p = 0; p < 128; p += 4) {
                s0 += ppart[((size_t)b * 128 + p + 0) * 256 + tid];
                s1 += ppart[((size_t)b * 128 + p + 1) * 256 + tid];
                s2 += ppart[((size_t)b * 128 + p + 2) * 256 + tid];
                s3 += ppart[((size_t)b * 128 + p + 3) * 256 + tid];
            }
            pl[tid] = ((s0 + s1) + (s2 + s3)) * (2.f / 16384.f);
            __syncthreads();
            float c0 = g1b[tid], c1 = 0.f, c2 = 0.f, c3 = 0.f;
            for (int k = 0; k < 256; k += 4) {
                c0 += pl[k + 0] * g1w[(k + 0) * 256 + tid];
                c1 += pl[k + 1] * g1w[(k + 1) * 256 + tid];
                c2 += pl[k + 2] * g1w[(k + 2) * 256 + tid];
                c3 += pl[k + 3] * g1w[(k + 3) * 256 + tid];
            }
            hid[tid] = fmaxf((c0 + c1) + (c2 + c3), 0.f);
            __syncthreads();
            float d0 = g2b[tid], d1 = 0.f, d2 = 0.f, d3 = 0.f;
            for (int k = 0; k < 256; k += 4) {
                d0 += hid[k + 0] * g2w[(k + 0) * 256 + tid];
                d1 += hid[k + 1] * g2w[(k + 1) * 256 + tid];
                d2 += hid[k + 2] * g2w[(k + 2) * 256 + tid];
                d3 += hid[k + 3] * g2w[(k + 3) * 256 + tid];
            }
            glob[b * 256 + tid] = (d0 + d1) + (d2 + d3);
            __syncthreads();
        }
        return;
    }

    ushort* As = smem;
    ushort* Bs = smem + 4096;

    const int lane = tid & 63;
    const int w = tid >> 6;
    const int wrow = w >> 1, wcol = w & 1;
    const int bx = blockIdx.x & 1;
    const int by = blockIdx.x >> 1;
    const int r0 = by * 128, n0 = bx * 128;
    const int l15 = lane & 15, l4 = lane >> 4;

    const int loff = lane * 16;
    char* ldsB0 = (char*)Bs + w * 2048;
    char* ldsB1 = (char*)Bs + w * 2048 + 1024;
    const int srow = tid >> 1, shalf = tid & 1;
    size_t agbase;
    {
        int r = r0 + srow;
        int b = r >> 14, rr = r & 16383;
        int ii = rr >> 7, jj = rr & 127;
        agbase = ((size_t)b * 65536 + (size_t)(2 * ii + 1) * 256 + (2 * jj + 1)) * 256 + shalf * 16;
    }

    f32x4 acc[4][4];
#pragma unroll
    for (int i = 0; i < 4; i++)
#pragma unroll
        for (int j = 0; j < 4; j++) acc[i][j] = (f32x4){0.f, 0.f, 0.f, 0.f};

    for (int ks = 0; ks < 8; ks++) {
        const char* btile = (const char*)Wt + (size_t)(bx * 8 + ks) * 8192;
        gload16(btile + w * 2048 + loff, ldsB0);
        gload16(btile + w * 2048 + 1024 + loff, ldsB1);
        {
            float4 f0 = *(const float4*)(key + agbase + (size_t)ks * 32);
            float4 f1 = *(const float4*)(key + agbase + (size_t)ks * 32 + 4);
            float4 f2 = *(const float4*)(key + agbase + (size_t)ks * 32 + 8);
            float4 f3 = *(const float4*)(key + agbase + (size_t)ks * 32 + 12);
            uint4 lo = {cvtpk(f0.x * 2.f, f0.y * 2.f), cvtpk(f0.z * 2.f, f0.w * 2.f),
                        cvtpk(f1.x * 2.f, f1.y * 2.f), cvtpk(f1.z * 2.f, f1.w * 2.f)};
            uint4 hi = {cvtpk(f2.x * 2.f, f2.y * 2.f), cvtpk(f2.z * 2.f, f2.w * 2.f),
                        cvtpk(f3.x * 2.f, f3.y * 2.f), cvtpk(f3.z * 2.f, f3.w * 2.f)};
            *(uint4*)((char*)As + srow * 64 + shalf * 32) = lo;
            *(uint4*)((char*)As + srow * 64 + shalf * 32 + 16) = hi;
        }
        __syncthreads();

        short8v a[4], bfr[4];
#pragma unroll
        for (int m = 0; m < 4; m++)
            a[m] = *(const short8v*)((const char*)As + (wrow * 64 + m * 16 + l15) * 64 + l4 * 16);
#pragma unroll
        for (int n = 0; n < 4; n++)
            bfr[n] = *(const short8v*)((const char*)Bs + (wcol * 64 + n * 16 + l15) * 64 + l4 * 16);
#pragma unroll
        for (int m = 0; m < 4; m++)
#pragma unroll
            for (int n = 0; n < 4; n++)
                acc[m][n] = __builtin_amdgcn_mfma_f32_16x16x32_bf16(a[m], bfr[n], acc[m][n], 0, 0, 0);
        __syncthreads();
    }

    float bv[4];
#pragma unroll
    for (int n = 0; n < 4; n++) bv[n] = bias[n0 + wcol * 64 + n * 16 + l15];
#pragma unroll
    for (int m = 0; m < 4; m++) {
#pragma unroll
        for (int n = 0; n < 4; n++) {
            int c = n0 + wcol * 64 + n * 16 + l15;
#pragma unroll
            for (int r = 0; r < 4; r++) {
                int R = r0 + wrow * 64 + m * 16 + l4 * 4 + r;
                float x = acc[m][n][r] + bv[n];
                Outp[(size_t)R * 256 + c] = f2bf(fmaxf(x, 0.f));
            }
        }
    }
}

// ---------------- bf16 MFMA mid GEMM (R16-exact, used for gemm2 only) ----------------
template <int AMODE, int EPI>
__global__ __launch_bounds__(256) void gemm_bf(const void* __restrict__ Asrc_,
                                               const ushort* __restrict__ Wt,
                                               const float* __restrict__ bias,
                                               void* __restrict__ Outp,
                                               const float* __restrict__ glob,
                                               const float* __restrict__ key) {
    __shared__ __align__(16) ushort smem[8192];   // As 8KB | Bs 8KB
    ushort* As = smem;
    ushort* Bs = smem + 4096;

    const int tid = threadIdx.x;
    const int lane = tid & 63;
    const int w = tid >> 6;
    const int wrow = w >> 1, wcol = w & 1;
    const int bx = blockIdx.x & 1;
    const int by = blockIdx.x >> 1;
    const int r0 = by * 128, n0 = bx * 128;
    const int l15 = lane & 15, l4 = lane >> 4;

    const int loff = lane * 16;
    char* ldsB0 = (char*)Bs + w * 2048;
    char* ldsB1 = (char*)Bs + w * 2048 + 1024;
    const int rowA0 = w * 32 + (lane >> 2);
    const int kbA = (lane & 3) * 16;
    char* ldsA0 = (char*)As + w * 2048;
    char* ldsA1 = (char*)As + w * 2048 + 1024;
    const int srow = tid >> 1, shalf = tid & 1;
    size_t agbase = 0;
    if constexpr (AMODE == 1) {
        int r = r0 + srow;
        int b = r >> 14, rr = r & 16383;
        int ii = rr >> 7, jj = rr & 127;
        agbase = ((size_t)b * 65536 + (size_t)(2 * ii + 1) * 256 + (2 * jj + 1)) * 256 + shalf * 16;
    }

    f32x4 acc[4][4];
#pragma unroll
    for (int i = 0; i < 4; i++)
#pragma unroll
        for (int j = 0; j < 4; j++) acc[i][j] = (f32x4){0.f, 0.f, 0.f, 0.f};

    for (int ks = 0; ks < 8; ks++) {
        const char* btile = (const char*)Wt + (size_t)(bx * 8 + ks) * 8192;
        gload16(btile + w * 2048 + loff, ldsB0);
        gload16(btile + w * 2048 + 1024 + loff, ldsB1);
        if constexpr (AMODE == 0) {
            const char* ab = (const char*)Asrc_;
            gload16(ab + (size_t)(r0 + rowA0) * 512 + ks * 64 + kbA, ldsA0);
            gload16(ab + (size_t)(r0 + rowA0 + 16) * 512 + ks * 64 + kbA, ldsA1);
        } else {
            const float* kf = (const float*)Asrc_;
            float4 f0 = *(const float4*)(kf + agbase + (size_t)ks * 32);
            float4 f1 = *(const float4*)(kf + agbase + (size_t)ks * 32 + 4);
            float4 f2 = *(const float4*)(kf + agbase + (size_t)ks * 32 + 8);
            float4 f3 = *(const float4*)(kf + agbase + (size_t)ks * 32 + 12);
            uint4 lo = {cvtpk(f0.x * 2.f, f0.y * 2.f), cvtpk(f0.z * 2.f, f0.w * 2.f),
                        cvtpk(f1.x * 2.f, f1.y * 2.f), cvtpk(f1.z * 2.f, f1.w * 2.f)};
            uint4 hi = {cvtpk(f2.x * 2.f, f2.y * 2.f), cvtpk(f2.z * 2.f, f2.w * 2.f),
                        cvtpk(f3.x * 2.f, f3.y * 2.f), cvtpk(f3.z * 2.f, f3.w * 2.f)};
            *(uint4*)((char*)As + srow * 64 + shalf * 32) = lo;
            *(uint4*)((char*)As + srow * 64 + shalf * 32 + 16) = hi;
        }
        __syncthreads();

        short8v a[4], bfr[4];
#pragma unroll
        for (int m = 0; m < 4; m++)
            a[m] = *(const short8v*)((const char*)As + (wrow * 64 + m * 16 + l15) * 64 + l4 * 16);
#pragma unroll
        for (int n = 0; n < 4; n++)
            bfr[n] = *(const short8v*)((const char*)Bs + (wcol * 64 + n * 16 + l15) * 64 + l4 * 16);
#pragma unroll
        for (int m = 0; m < 4; m++)
#pragma unroll
            for (int n = 0; n < 4; n++)
                acc[m][n] = __builtin_amdgcn_mfma_f32_16x16x32_bf16(a[m], bfr[n], acc[m][n], 0, 0, 0);
        __syncthreads();
    }

    const int b = r0 >> 14;
    float bv[4], gv[4];
#pragma unroll
    for (int n = 0; n < 4; n++) {
        int c = n0 + wcol * 64 + n * 16 + l15;
        bv[n] = bias[c];
        if constexpr (EPI == 1) gv[n] = glob[b * 256 + c];
    }
#pragma unroll
    for (int m = 0; m < 4; m++) {
#pragma unroll
        for (int n = 0; n < 4; n++) {
            int c = n0 + wcol * 64 + n * 16 + l15;
#pragma unroll
            for (int r = 0; r < 4; r++) {
                int row = wrow * 64 + m * 16 + l4 * 4 + r;
                int R = r0 + row;
                float x = acc[m][n][r] + bv[n];
                if constexpr (EPI == 0) {
                    ((ushort*)Outp)[(size_t)R * 256 + c] = f2bf(fmaxf(x, 0.f));
                } else {
                    int rr = R & 16383;
                    int ii = rr >> 7, jj = rr & 127;
                    size_t kb = ((size_t)b * 65536 + (size_t)(2 * ii) * 256 + 2 * jj) * 256 + c;
                    float ka = key[kb];
                    float kb2 = key[kb + 256];
                    float kc2 = key[kb + 65536];
                    float kd2 = key[kb + 65536 + 256];
                    float low = 0.5f * (ka + kb2 + kc2 + kd2);
                    float high = 0.5f * (3.f * kd2 - ka - kb2 - kc2);
                    float wei = 1.f / (1.f + __expf(-(x + gv[n])));
                    ((ushort*)Outp)[(size_t)R * 256 + c] = f2bf(wei * high + low);
                }
            }
        }
    }
}

// ---------------- batched K/V GEMM (R16-exact) ----------------
__global__ __launch_bounds__(256) void gemm_bf34(const ushort* __restrict__ Afre,
                                                 const ushort* __restrict__ kwt,
                                                 const ushort* __restrict__ vwt,
                                                 const float* __restrict__ kbias,
                                                 const float* __restrict__ vbias,
                                                 ushort* __restrict__ Km,
                                                 ushort* __restrict__ Vn) {
    __shared__ __align__(16) ushort smem[8192];   // As 8KB | Bs 8KB
    ushort* As = smem;
    ushort* Bs = smem + 4096;

    const int isV = blockIdx.x >= 512;
    const int blk = blockIdx.x & 511;
    const ushort* Wt = isV ? vwt : kwt;
    const float* bias = isV ? vbias : kbias;
    ushort* Outp = isV ? Vn : Km;

    const int tid = threadIdx.x;
    const int lane = tid & 63;
    const int w = tid >> 6;
    const int wrow = w >> 1, wcol = w & 1;
    const int bx = blk & 1;
    const int by = blk >> 1;
    const int r0 = by * 128, n0 = bx * 128;
    const int l15 = lane & 15, l4 = lane >> 4;

    const int loff = lane * 16;
    char* ldsB0 = (char*)Bs + w * 2048;
    char* ldsB1 = (char*)Bs + w * 2048 + 1024;
    const int rowA0 = w * 32 + (lane >> 2);
    const int kbA = (lane & 3) * 16;
    char* ldsA0 = (char*)As + w * 2048;
    char* ldsA1 = (char*)As + w * 2048 + 1024;

    f32x4 acc[4][4];
#pragma unroll
    for (int i = 0; i < 4; i++)
#pragma unroll
        for (int j = 0; j < 4; j++) acc[i][j] = (f32x4){0.f, 0.f, 0.f, 0.f};

    for (int ks = 0; ks < 8; ks++) {
        const char* btile = (const char*)Wt + (size_t)(bx * 8 + ks) * 8192;
        gload16(btile + w * 2048 + loff, ldsB0);
        gload16(btile + w * 2048 + 1024 + loff, ldsB1);
        const char* ab = (const char*)Afre;
        gload16(ab + (size_t)(r0 + rowA0) * 512 + ks * 64 + kbA, ldsA0);
        gload16(ab + (size_t)(r0 + rowA0 + 16) * 512 + ks * 64 + kbA, ldsA1);
        __syncthreads();

        short8v a[4], bfr[4];
#pragma unroll
        for (int m = 0; m < 4; m++)
            a[m] = *(const short8v*)((const char*)As + (wrow * 64 + m * 16 + l15) * 64 + l4 * 16);
#pragma unroll
        for (int n = 0; n < 4; n++)
            bfr[n] = *(const short8v*)((const char*)Bs + (wcol * 64 + n * 16 + l15) * 64 + l4 * 16);
#pragma unroll
        for (int m = 0; m < 4; m++)
#pragma unroll
            for (int n = 0; n < 4; n++)
                acc[m][n] = __builtin_amdgcn_mfma_f32_16x16x32_bf16(a[m], bfr[n], acc[m][n], 0, 0, 0);
        __syncthreads();
    }

    float bv[4];
#pragma unroll
    for (int n = 0; n < 4; n++) bv[n] = bias[n0 + wcol * 64 + n * 16 + l15];
#pragma unroll
    for (int m = 0; m < 4; m++) {
#pragma unroll
        for (int n = 0; n < 4; n++) {
            int c = n0 + wcol * 64 + n * 16 + l15;
#pragma unroll
            for (int r = 0; r < 4; r++) {
                int R = r0 + wrow * 64 + m * 16 + l4 * 4 + r;
                float x = acc[m][n][r] + bv[n];
                float o = isV ? x : ((x > 0.f) ? x + 1.f : __expf(x));
                Outp[(size_t)R * 256 + c] = f2bf(o);
            }
        }
    }
}

// ---------------- KV partials (bf16 in, R7-exact 8-row stages) ----------------
__global__ __launch_bounds__(256) void k_kv_part(const ushort* __restrict__ Km,
                                                 const ushort* __restrict__ Vn,
                                                 float* __restrict__ kvp,
                                                 float* __restrict__ ksp) {
    __shared__ float Kl[8][33];
    __shared__ float Vl[8][33];
    int t = threadIdx.x;
    int c = blockIdx.x & 31, h = (blockIdx.x >> 5) & 7, b = blockIdx.x >> 8;
    int d = t >> 3, vq = (t & 7) * 4;
    int lr = t >> 5, lc = t & 31;
    float acc0 = 0, acc1 = 0, acc2 = 0, acc3 = 0, ks = 0;
    size_t rowbase = (size_t)b * 16384 + (size_t)c * 512;
    for (int s0 = 0; s0 < 512; s0 += 8) {
        size_t idx = (rowbase + s0 + lr) * 256 + h * 32 + lc;
        Kl[lr][lc] = bf2f(Km[idx]);
        Vl[lr][lc] = bf2f(Vn[idx]);
        __syncthreads();
#pragma unroll
        for (int rr = 0; rr < 8; rr++) {
            float kd = Kl[rr][d];
            acc0 += kd * Vl[rr][vq];
            acc1 += kd * Vl[rr][vq + 1];
            acc2 += kd * Vl[rr][vq + 2];
            acc3 += kd * Vl[rr][vq + 3];
            ks += kd;
        }
        __syncthreads();
    }
    size_t ob = ((size_t)(b * 8 + h) * 32 + c) * 1024 + d * 32 + vq;
    kvp[ob] = acc0; kvp[ob + 1] = acc1; kvp[ob + 2] = acc2; kvp[ob + 3] = acc3;
    if ((t & 7) == 0) ksp[((b * 8 + h) * 32 + c) * 32 + d] = ks;
}

// ---------------- KV reduce -> bf16 augmented B^T: KVt[bh][48][32] (R7-exact) ----------------
__global__ __launch_bounds__(256) void k_kv_reduce(const float* __restrict__ kvp,
                                                   const float* __restrict__ ksp,
                                                   ushort* __restrict__ kvt) {
    int bh = blockIdx.x, t = threadIdx.x;
    for (int e = t; e < 1024; e += 256) {
        float s = 0.f;
        for (int cc = 0; cc < 32; cc++) s += kvp[((size_t)bh * 32 + cc) * 1024 + e];
        int d = e >> 5, v = e & 31;
        kvt[((size_t)bh * 48 + v) * 32 + d] = f2bf(s);
    }
    if (t < 32) {
        float s = 0.f;
        for (int cc = 0; cc < 32; cc++) s += ksp[(bh * 32 + cc) * 32 + t];
        kvt[((size_t)bh * 48 + 32) * 32 + t] = f2bf(s);
    }
    for (int z = t; z < 480; z += 256) kvt[(size_t)bh * 48 * 32 + 33 * 32 + z] = 0;
}

// ---------------- MFMA q-GEMM (BM=128, BN=256, BK=32), 2-phase pipelined (R7 BEST, byte-exact) ----------------
__global__ __launch_bounds__(512, 4) void k_qattn_mfma(const float* __restrict__ query,
                                                       const ushort* __restrict__ wfp,
                                                       const float* __restrict__ qb,
                                                       const ushort* __restrict__ kvt,
                                                       float* __restrict__ Out) {
    __shared__ __align__(16) char smem[65536];
    char* As0 = smem;                // [128][32] f32 (16KB)
    char* As1 = smem + 16384;
    char* Bs0 = smem + 32768;        // [256][32] bf16 (16KB)
    char* Bs1 = smem + 49152;

    const int tid = threadIdx.x;
    const int lane = tid & 63;
    const int wid = tid >> 6;            // 0..7
    const int wrow = wid >> 2, wcol = wid & 3;
    const int R0 = blockIdx.x * 128;
    const int l15 = lane & 15, l4 = lane >> 4;

    const int arow0 = wid * 16 + (lane >> 3);
    const int achunk = (lane & 7) ^ (lane >> 3);
    const float* aga = query + (size_t)(R0 + arow0) * 512 + achunk * 4;
    const int wb = wid * 2048;
    const int bglo = wb + lane * 16;

    f32x4 acc[4][4];
#pragma unroll
    for (int i = 0; i < 4; i++)
#pragma unroll
        for (int j = 0; j < 4; j++) acc[i][j] = (f32x4){0.f, 0.f, 0.f, 0.f};

#define QSTAGE(dA, dB, kss)                                                     \
    do {                                                                        \
        const float* ga_ = aga + (size_t)(kss) * 32;                            \
        gload16(ga_, (dA) + wb);                                                \
        gload16(ga_ + 8 * 512, (dA) + wb + 1024);                               \
        const char* pan_ = (const char*)wfp + (size_t)(kss) * 16384 + bglo;     \
        gload16(pan_, (dB) + wb);                                               \
        gload16(pan_ + 1024, (dB) + wb + 1024);                                 \
    } while (0)

    QSTAGE(As0, Bs0, 0);
    asm volatile("s_waitcnt vmcnt(0)" ::: "memory");
    __builtin_amdgcn_s_barrier();
    __builtin_amdgcn_sched_barrier(0);

    for (int ks = 0; ks < 16; ks++) {
        const char* bA = (ks & 1) ? As1 : As0;
        const char* bB = (ks & 1) ? Bs1 : Bs0;
        char* nA = (ks & 1) ? As0 : As1;
        char* nB = (ks & 1) ? Bs0 : Bs1;
        if (ks < 15) QSTAGE(nA, nB, ks + 1);

        short8v bfr[4];
#pragma unroll
        for (int n = 0; n < 4; n++)
            bfr[n] = *(const short8v*)(bB + (wcol * 64 + n * 16 + l15) * 64 + l4 * 16);
#pragma unroll
        for (int m = 0; m < 4; m++) {
            int row = wrow * 64 + m * 16 + l15;
            int j0 = (l4 * 2) ^ (l15 & 7);
            const char* rp = bA + row * 128;
            f32x4 lo = *(const f32x4*)(rp + j0 * 16);
            f32x4 hi = *(const f32x4*)(rp + (j0 ^ 1) * 16);
            union { uint4 u; short8v s; } av;
            av.u = (uint4){cvtpk(lo.x, lo.y), cvtpk(lo.z, lo.w),
                           cvtpk(hi.x, hi.y), cvtpk(hi.z, hi.w)};
#pragma unroll
            for (int n = 0; n < 4; n++)
                acc[m][n] = __builtin_amdgcn_mfma_f32_16x16x32_bf16(av.s, bfr[n], acc[m][n], 0, 0, 0);
        }

        if (ks < 15) {
            asm volatile("s_waitcnt vmcnt(0)" ::: "memory");
            __builtin_amdgcn_s_barrier();
            __builtin_amdgcn_sched_barrier(0);
        }
    }
#undef QSTAGE

    __syncthreads();

    float qbv[4];
#pragma unroll
    for (int n = 0; n < 4; n++) qbv[n] = qb[wcol * 64 + n * 16 + l15];
#pragma unroll
    for (int m = 0; m < 4; m++) {
#pragma unroll
        for (int n = 0; n < 4; n++) {
#pragma unroll
            for (int r = 0; r < 4; r++) {
                int rl = m * 16 + l4 * 4 + r;
                int cl = n * 16 + l15;
                float x = acc[m][n][r] + qbv[n];
                float q = x > 0.f ? x + 1.f : __expf(x);
                int byte = wid * 8192 + ((rl * 128 + cl * 2) ^ ((rl & 7) << 4));
                *(ushort*)(smem + byte) = f2bf(q);
            }
        }
    }
    __syncthreads();

    const int bb = R0 >> 16;
#pragma unroll
    for (int hi = 0; hi < 2; hi++) {
        int h = wcol * 2 + hi;
        int bh = bb * 8 + h;
        const ushort* kb = kvt + (size_t)bh * 48 * 32;
        short8v bk0 = *(const short8v*)(kb + (0 * 16 + l15) * 32 + l4 * 8);
        short8v bk1 = *(const short8v*)(kb + (1 * 16 + l15) * 32 + l4 * 8);
        short8v bkz = *(const short8v*)(kb + (2 * 16 + l15) * 32 + l4 * 8);
#pragma unroll
        for (int m = 0; m < 4; m++) {
            int rl = m * 16 + l15;
            int byte = wid * 8192 + ((rl * 128 + hi * 64 + l4 * 16) ^ ((rl & 7) << 4));
            short8v aq = *(const short8v*)(smem + byte);
            f32x4 zero = (f32x4){0.f, 0.f, 0.f, 0.f};
            f32x4 o0 = __builtin_amdgcn_mfma_f32_16x16x32_bf16(aq, bk0, zero, 0, 0, 0);
            f32x4 o1 = __builtin_amdgcn_mfma_f32_16x16x32_bf16(aq, bk1, zero, 0, 0, 0);
            f32x4 oz = __builtin_amdgcn_mfma_f32_16x16x32_bf16(aq, bkz, zero, 0, 0, 0);
#pragma unroll
            for (int r = 0; r < 4; r++) {
                float z = __shfl(oz[r], (lane & 48));
                float sc = 1.f / (z + 1e-6f);
                int grow = R0 + wrow * 64 + m * 16 + l4 * 4 + r;
                int gcol = wcol * 64 + hi * 32 + l15;
                Out[(size_t)grow * 256 + gcol] = o0[r] * sc;
                Out[(size_t)grow * 256 + gcol + 16] = o1[r] * sc;
            }
        }
    }
}

extern "C" void kernel_launch(void* const* d_in, const int* in_sizes, int n_in,
                              void* d_out, int out_size, void* d_ws, size_t ws_size,
                              hipStream_t stream) {
    const float* query = (const float*)d_in[0];
    const float* key = (const float*)d_in[1];
    // d_in[2] = value: only its shape is used by the reference — never read.
    const float* mh = (const float*)d_in[3];
    const float* q_w = (const float*)d_in[4];
    const float* q_b = (const float*)d_in[5];
    const float* k_w = (const float*)d_in[6];
    const float* k_b = (const float*)d_in[7];
    const float* v_w = (const float*)d_in[8];
    const float* v_b = (const float*)d_in[9];
    const float* l1_w = (const float*)d_in[10];
    const float* l1_b = (const float*)d_in[11];
    const float* l2_w = (const float*)d_in[12];
    const float* l2_b = (const float*)d_in[13];
    const float* g1_w = (const float*)d_in[14];
    const float* g1_b = (const float*)d_in[15];
    const float* g2_w = (const float*)d_in[16];
    const float* g2_b = (const float*)d_in[17];

    float* out = (float*)d_out;
    float* ws = (float*)d_ws;

    float* ppart = ws + WS_PPART;
    float* glob = ws + WS_GLOB;
    float* kvp = ws + WS_KVP;
    float* ksp = ws + WS_KSP;
    ushort* kvt = (ushort*)(ws + WS_KVT);
    ushort* wfp = (ushort*)(ws + WS_WFP);
    ushort* l1t = (ushort*)(ws + WS_L1T);
    ushort* l2t = (ushort*)(ws + WS_L2T);
    ushort* kwt = (ushort*)(ws + WS_KWT);
    ushort* vwt = (ushort*)(ws + WS_VWT);

    // big intermediates inside d_out (qattn overwrites everything at the end)
    ushort* t = (ushort*)out;                      // 32768x256 bf16
    ushort* fre = (ushort*)(out + 4194304);        // 32768x256 bf16
    ushort* Km = (ushort*)(out + 8388608);         // 32768x256 bf16
    ushort* Vn = (ushort*)(out + 12582912);        // 32768x256 bf16

    k_prep<<<1792, 256, 0, stream>>>(l1_w, l2_w, k_w, v_w, mh, q_w, key,
                                     l1t, l2t, kwt, vwt, wfp, ppart);

    // t = relu(s @ l1_w + l1_b)  (blocks 0..511)  +  glob MLP (block 512), both dep only on prep
    gemm1_glob<<<513, 256, 0, stream>>>(key, l1t, l1_b, t,
                                        ppart, g1_w, g1_b, g2_w, g2_b, glob);

    // fre = sigmoid(t @ l2_w + l2_b + glob) * high + low
    gemm_bf<0, 1><<<512, 256, 0, stream>>>(t, l2t, l2_b, fre, glob, key);
    // Km = elu(fre@k_w+k_b)+1  and  Vn = fre@v_w+v_b  in ONE batched launch
    gemm_bf34<<<1024, 256, 0, stream>>>(fre, kwt, vwt, k_b, v_b, Km, Vn);

    k_kv_part<<<512, 256, 0, stream>>>(Km, Vn, kvp, ksp);
    k_kv_reduce<<<16, 256, 0, stream>>>(kvp, ksp, kvt);

    k_qattn_mfma<<<1024, 512, 0, stream>>>(query, wfp, q_b, kvt, out);
}